// Round 1
// baseline (1277.718 us; speedup 1.0000x reference)
//
#include <hip/hip_runtime.h>
#include <math.h>

#define F 512
#define H 16
#define C 7

// ---------------- utility ----------------
__global__ void zero_i32(int* p, int n) {
    int i = blockIdx.x * blockDim.x + threadIdx.x;
    if (i < n) p[i] = 0;
}

// ---------------- CSR build ----------------
__global__ void hist_kernel(const int* __restrict__ ei, int E, int Etot, int* __restrict__ cnt) {
    int e = blockIdx.x * blockDim.x + threadIdx.x;
    if (e >= Etot) return;
    int dst = (e < E) ? ei[E + e] : (e - E);
    atomicAdd(&cnt[dst], 1);
}

// block = 1024 threads; exclusive scan within block, block totals to partials
__global__ void scan_blocks(const int* __restrict__ in, int n, int* __restrict__ out,
                            int* __restrict__ partials) {
    __shared__ int sums[16];
    int t = threadIdx.x;
    int gid = blockIdx.x * 1024 + t;
    int orig = (gid < n) ? in[gid] : 0;
    int v = orig;
    int lane = t & 63, wid = t >> 6;
    for (int d = 1; d < 64; d <<= 1) {
        int u = __shfl_up(v, d);
        if (lane >= d) v += u;
    }
    if (lane == 63) sums[wid] = v;
    __syncthreads();
    if (wid == 0) {
        int s = (lane < 16) ? sums[lane] : 0;
        for (int d = 1; d < 16; d <<= 1) {
            int u = __shfl_up(s, d);
            if (lane >= d) s += u;
        }
        if (lane < 16) sums[lane] = s;
    }
    __syncthreads();
    int off = (wid > 0) ? sums[wid - 1] : 0;
    v += off;
    if (gid < n) out[gid] = v - orig;           // exclusive within block
    if (partials && t == 1023) partials[blockIdx.x] = v;  // block total
}

__global__ void scan_apply(int* __restrict__ rp, const int* __restrict__ part_excl,
                           int n, int Etot, int* __restrict__ cursor) {
    int gid = blockIdx.x * 1024 + threadIdx.x;
    if (gid < n) {
        int v = rp[gid] + part_excl[blockIdx.x];
        rp[gid] = v;
        cursor[gid] = v;
    }
    if (gid == 0) rp[n] = Etot;
}

__global__ void scatter_kernel(const int* __restrict__ ei, int E, int Etot,
                               int* __restrict__ cursor, int* __restrict__ srcs) {
    int e = blockIdx.x * blockDim.x + threadIdx.x;
    if (e >= Etot) return;
    int src, dst;
    if (e < E) { src = ei[e]; dst = ei[E + e]; }
    else       { src = e - E; dst = e - E; }
    int pos = atomicAdd(&cursor[dst], 1);
    srcs[pos] = src;
}

// ---------------- lin1: h = relu(x @ W1^T + b1), plus rn = 1/max(||h||,eps) ----------------
// block 256: j = t&15 (output feature), g = t>>4 (node group of 4); block covers 64 nodes.
__global__ __launch_bounds__(256) void lin1_relu(const float* __restrict__ x,
                                                 const float* __restrict__ W1,
                                                 const float* __restrict__ b1,
                                                 float* __restrict__ h,
                                                 float* __restrict__ rn, int N) {
    __shared__ float w[H * 516];  // padded rows: 516 floats -> 2-way-max bank aliasing
    int t = threadIdx.x;
    for (int idx = t; idx < H * F / 4; idx += 256) {
        int f = idx * 4;
        int row = f >> 9;       // /512
        int col = f & 511;
        float4 v = *(const float4*)(W1 + f);
        *(float4*)(w + row * 516 + col) = v;
    }
    __syncthreads();

    int j = t & 15, g = t >> 4;
    int i0 = blockIdx.x * 64 + g * 4;

    const float* x0 = x + (size_t)min(i0 + 0, N - 1) * F;
    const float* x1 = x + (size_t)min(i0 + 1, N - 1) * F;
    const float* x2 = x + (size_t)min(i0 + 2, N - 1) * F;
    const float* x3 = x + (size_t)min(i0 + 3, N - 1) * F;
    const float* wr = w + j * 516;

    float acc0 = 0.f, acc1 = 0.f, acc2 = 0.f, acc3 = 0.f;
    for (int k = 0; k < F; k += 4) {
        float4 wv = *(const float4*)(wr + k);
        float4 a = *(const float4*)(x0 + k);
        float4 b = *(const float4*)(x1 + k);
        float4 c = *(const float4*)(x2 + k);
        float4 d = *(const float4*)(x3 + k);
        acc0 += wv.x * a.x + wv.y * a.y + wv.z * a.z + wv.w * a.w;
        acc1 += wv.x * b.x + wv.y * b.y + wv.z * b.z + wv.w * b.w;
        acc2 += wv.x * c.x + wv.y * c.y + wv.z * c.z + wv.w * c.w;
        acc3 += wv.x * d.x + wv.y * d.y + wv.z * d.z + wv.w * d.w;
    }
    float bj = b1[j];
    float accs[4] = {acc0, acc1, acc2, acc3};
    for (int n = 0; n < 4; ++n) {
        int i = i0 + n;
        if (i >= N) break;  // uniform across the 16-lane group
        float v = fmaxf(accs[n] + bj, 0.f);
        h[(size_t)i * H + j] = v;
        float sq = v * v;
        sq += __shfl_xor(sq, 1);
        sq += __shfl_xor(sq, 2);
        sq += __shfl_xor(sq, 4);
        sq += __shfl_xor(sq, 8);
        if (j == 0) rn[i] = 1.0f / fmaxf(sqrtf(sq), 1e-12f);
    }
}

// ---------------- AGNN step ----------------
// 16 lanes per dst node; lane = feature. Gathers h[src] rows via CSR, no atomics.
__global__ __launch_bounds__(256) void agnn_step(const float* __restrict__ h,
                                                 const float* __restrict__ rn,
                                                 const int* __restrict__ rp,
                                                 const int* __restrict__ srcs,
                                                 const float* __restrict__ bp,
                                                 float* __restrict__ h_out,
                                                 float* __restrict__ rn_out, int N) {
    int t = threadIdx.x;
    int lane = t & 15, grp = t >> 4;
    int i = blockIdx.x * 16 + grp;
    if (i >= N) return;

    const float L2E = 1.4426950408889634f;
    float beta = bp ? bp[0] : 1.0f;
    float hi = h[(size_t)i * H + lane];
    float rni = rn[i];
    float a = beta * rni * L2E;      // logit*L2E = a * rns * p
    float mm = fabsf(beta) * L2E;    // subtract |beta| (shift-invariant softmax)

    int e = rp[i], end = rp[i + 1];
    float denom = 0.f, acc = 0.f;

    // software-pipelined gather loop (one-ahead prefetch)
    int s = srcs[e];
    float hs = h[(size_t)s * H + lane];
    float rns = rn[s];
    for (;;) {
        int e2 = e + 1;
        int s2 = 0; float hs2 = 0.f, rns2 = 0.f;
        if (e2 < end) {
            s2 = srcs[e2];
            hs2 = h[(size_t)s2 * H + lane];
            rns2 = rn[s2];
        }
        float p = hi * hs;
        p += __shfl_xor(p, 1);
        p += __shfl_xor(p, 2);
        p += __shfl_xor(p, 4);
        p += __shfl_xor(p, 8);
        float wgt = exp2f(a * rns * p - mm);
        denom += wgt;
        acc = fmaf(wgt, hs, acc);
        if (e2 >= end) break;
        e = e2; s = s2; hs = hs2; rns = rns2;
    }

    float o = acc / denom;
    h_out[(size_t)i * H + lane] = o;
    float sq = o * o;
    sq += __shfl_xor(sq, 1);
    sq += __shfl_xor(sq, 2);
    sq += __shfl_xor(sq, 4);
    sq += __shfl_xor(sq, 8);
    if (lane == 0) rn_out[i] = 1.0f / fmaxf(sqrtf(sq), 1e-12f);
}

// ---------------- head: logits + log_softmax ----------------
__global__ __launch_bounds__(256) void head_kernel(const float* __restrict__ h,
                                                   const float* __restrict__ W2,
                                                   const float* __restrict__ b2,
                                                   float* __restrict__ out, int N) {
    __shared__ float w2[C * H];
    __shared__ float bb[C];
    int t = threadIdx.x;
    if (t < C * H) w2[t] = W2[t];
    if (t < C) bb[t] = b2[t];
    __syncthreads();
    int i = blockIdx.x * blockDim.x + t;
    if (i >= N) return;
    const float4* hp = (const float4*)(h + (size_t)i * H);
    float4 h0 = hp[0], h1 = hp[1], h2 = hp[2], h3 = hp[3];
    float lg[C];
    float m = -1e30f;
    for (int c = 0; c < C; ++c) {
        const float4* wp = (const float4*)(w2 + c * H);
        float4 w0 = wp[0], w1 = wp[1], w2v = wp[2], w3 = wp[3];
        float s = h0.x * w0.x + h0.y * w0.y + h0.z * w0.z + h0.w * w0.w
                + h1.x * w1.x + h1.y * w1.y + h1.z * w1.z + h1.w * w1.w
                + h2.x * w2v.x + h2.y * w2v.y + h2.z * w2v.z + h2.w * w2v.w
                + h3.x * w3.x + h3.y * w3.y + h3.z * w3.z + h3.w * w3.w;
        s += bb[c];
        lg[c] = s;
        m = fmaxf(m, s);
    }
    float sum = 0.f;
    for (int c = 0; c < C; ++c) sum += expf(lg[c] - m);
    float lse = m + logf(sum);
    float* op = out + (size_t)i * C;
    for (int c = 0; c < C; ++c) op[c] = lg[c] - lse;
}

// ---------------- launch ----------------
extern "C" void kernel_launch(void* const* d_in, const int* in_sizes, int n_in,
                              void* d_out, int out_size, void* d_ws, size_t ws_size,
                              hipStream_t stream) {
    const float* x     = (const float*)d_in[0];
    const int*   ei    = (const int*)d_in[1];
    const float* W1    = (const float*)d_in[2];
    const float* b1    = (const float*)d_in[3];
    const float* beta2 = (const float*)d_in[4];
    const float* beta3 = (const float*)d_in[5];
    const float* beta4 = (const float*)d_in[6];
    const float* W2    = (const float*)d_in[7];
    const float* b2    = (const float*)d_in[8];
    float* out = (float*)d_out;

    int N = in_sizes[0] / F;     // 100000
    int E = in_sizes[1] / 2;     // 3200000
    int Etot = E + N;

    char* p = (char*)d_ws;
    float* h_a  = (float*)p; p += (size_t)N * H * 4;
    float* h_b  = (float*)p; p += (size_t)N * H * 4;
    float* rn_a = (float*)p; p += (size_t)N * 4;
    float* rn_b = (float*)p; p += (size_t)N * 4;
    int* cnt    = (int*)p;   p += (size_t)N * 4;
    int* rp     = (int*)p;   p += (size_t)(N + 1) * 4;
    int* cursor = (int*)p;   p += (size_t)N * 4;
    int* part   = (int*)p;   p += 4096;
    int* srcs   = (int*)p;   p += (size_t)Etot * 4;

    int nblk_scan = (N + 1023) / 1024;

    // CSR build
    zero_i32<<<(N + 255) / 256, 256, 0, stream>>>(cnt, N);
    hist_kernel<<<(Etot + 255) / 256, 256, 0, stream>>>(ei, E, Etot, cnt);
    scan_blocks<<<nblk_scan, 1024, 0, stream>>>(cnt, N, rp, part);
    scan_blocks<<<1, 1024, 0, stream>>>(part, nblk_scan, part, nullptr);
    scan_apply<<<nblk_scan, 1024, 0, stream>>>(rp, part, N, Etot, cursor);
    scatter_kernel<<<(Etot + 255) / 256, 256, 0, stream>>>(ei, E, Etot, cursor, srcs);

    // lin1 + initial norms
    lin1_relu<<<(N + 63) / 64, 256, 0, stream>>>(x, W1, b1, h_a, rn_a, N);

    // 4 AGNN steps (beta1 fixed at 1.0 -> nullptr)
    int gs = (N + 15) / 16;
    agnn_step<<<gs, 256, 0, stream>>>(h_a, rn_a, rp, srcs, nullptr, h_b, rn_b, N);
    agnn_step<<<gs, 256, 0, stream>>>(h_b, rn_b, rp, srcs, beta2, h_a, rn_a, N);
    agnn_step<<<gs, 256, 0, stream>>>(h_a, rn_a, rp, srcs, beta3, h_b, rn_b, N);
    agnn_step<<<gs, 256, 0, stream>>>(h_b, rn_b, rp, srcs, beta4, h_a, rn_a, N);

    // head
    head_kernel<<<(N + 255) / 256, 256, 0, stream>>>(h_a, W2, b2, out, N);
}

// Round 2
// 1014.362 us; speedup vs baseline: 1.2596x; 1.2596x over previous
//
#include <hip/hip_runtime.h>
#include <math.h>

#define F 512
#define H 16
#define C 7
#define NB 512          // coarse buckets for CSR build (width = ceil(N/NB) must be <= 256)
#define BIN_CHUNK 4096  // edges per block in bin_edges

// ---------------- utility ----------------
__global__ void zero_i32(int* p, int n) {
    int i = blockIdx.x * blockDim.x + threadIdx.x;
    if (i < n) p[i] = 0;
}

// ---------------- CSR build: two-level LDS-binned counting sort ----------------
// K1: coarse bucket histogram (LDS-staged, 512 global atomics per block)
__global__ __launch_bounds__(256) void bucket_hist(const int* __restrict__ ei, int E, int Etot,
                                                   int width, int* __restrict__ gcnt) {
    __shared__ int h[NB];
    for (int i = threadIdx.x; i < NB; i += 256) h[i] = 0;
    __syncthreads();
    int stride = gridDim.x * 256;
    for (int e = blockIdx.x * 256 + threadIdx.x; e < Etot; e += stride) {
        int dst = (e < E) ? ei[E + e] : (e - E);
        atomicAdd(&h[dst / width], 1);
    }
    __syncthreads();
    for (int i = threadIdx.x; i < NB; i += 256)
        if (h[i]) atomicAdd(&gcnt[i], h[i]);
}

// K2: exclusive scan of 512 bucket counts (one block of NB threads)
__global__ void bucket_scan(const int* __restrict__ gcnt, int Etot,
                            int* __restrict__ bbase, int* __restrict__ gcur,
                            int* __restrict__ rp, int N) {
    __shared__ int s[NB];
    int t = threadIdx.x;
    int own = gcnt[t];
    s[t] = own;
    __syncthreads();
    for (int d = 1; d < NB; d <<= 1) {
        int add = (t >= d) ? s[t - d] : 0;
        __syncthreads();
        s[t] += add;
        __syncthreads();
    }
    int excl = s[t] - own;
    bbase[t] = excl;
    gcur[t] = excl;
    if (t == NB - 1) bbase[NB] = s[t];  // == Etot
    if (t == 0) rp[N] = Etot;
}

// K3: bin edges into buckets; packed word = src | (dstLocal << 17)
//     (requires N <= 2^17 and width <= 2^15 — holds for N=100000, width=196)
__global__ __launch_bounds__(256) void bin_edges(const int* __restrict__ ei, int E, int Etot,
                                                 int width, int* __restrict__ gcur,
                                                 unsigned* __restrict__ binned) {
    __shared__ int cnt[NB];
    __shared__ int base[NB];
    int t = threadIdx.x;
    for (int i = t; i < NB; i += 256) cnt[i] = 0;
    __syncthreads();
    long chunk0 = (long)blockIdx.x * BIN_CHUNK;
    // pass 1: count buckets in this chunk
    for (int k = 0; k < BIN_CHUNK / 256; ++k) {
        long e = chunk0 + k * 256 + t;
        if (e < Etot) {
            int dst = (e < E) ? ei[E + e] : (int)(e - E);
            atomicAdd(&cnt[dst / width], 1);
        }
    }
    __syncthreads();
    // reserve global space per bucket
    for (int i = t; i < NB; i += 256) {
        int c = cnt[i];
        base[i] = c ? atomicAdd(&gcur[i], c) : 0;
        cnt[i] = 0;
    }
    __syncthreads();
    // pass 2: write packed edges (runs of ~8 consecutive words per bucket)
    for (int k = 0; k < BIN_CHUNK / 256; ++k) {
        long e = chunk0 + k * 256 + t;
        if (e < Etot) {
            int src, dst;
            if (e < E) { src = ei[e]; dst = ei[E + e]; }
            else       { src = (int)(e - E); dst = src; }
            int b = dst / width;
            int pos = base[b] + atomicAdd(&cnt[b], 1);
            binned[pos] = (unsigned)src | ((unsigned)(dst - b * width) << 17);
        }
    }
}

// K4: per-bucket counting sort (one workgroup per bucket). Writes rp + srcs.
//     Scatter targets live in the bucket's ~26 KB srcs region -> no write amplification.
__global__ __launch_bounds__(256) void bucket_sort(const unsigned* __restrict__ binned,
                                                   const int* __restrict__ bbase,
                                                   int width, int N,
                                                   int* __restrict__ rp, int* __restrict__ srcs) {
    __shared__ int cnt[256];
    __shared__ int cur[256];
    int b = blockIdx.x, t = threadIdx.x;
    int r0 = bbase[b], r1 = bbase[b + 1];
    int nodeBase = b * width;
    cnt[t] = 0;
    cur[t] = 0;
    __syncthreads();
    for (int e = r0 + t; e < r1; e += 256) {
        unsigned p = binned[e];
        atomicAdd(&cnt[p >> 17], 1);
    }
    __syncthreads();
    int own = cnt[t];
    for (int d = 1; d < 256; d <<= 1) {
        int add = (t >= d) ? cnt[t - d] : 0;
        __syncthreads();
        cnt[t] += add;
        __syncthreads();
    }
    int excl = cnt[t] - own;
    int node = nodeBase + t;
    if (t < width && node < N) rp[node] = r0 + excl;
    __syncthreads();
    cnt[t] = excl;
    __syncthreads();
    for (int e = r0 + t; e < r1; e += 256) {
        unsigned p = binned[e];
        int dL = p >> 17;
        int pos = r0 + cnt[dL] + atomicAdd(&cur[dL], 1);
        srcs[pos] = (int)(p & 0x1FFFFu);
    }
}

// ---------------- lin1: h = relu(x @ W1^T + b1), plus rn = 1/max(||h||,eps) ----------------
__global__ __launch_bounds__(256) void lin1_relu(const float* __restrict__ x,
                                                 const float* __restrict__ W1,
                                                 const float* __restrict__ b1,
                                                 float* __restrict__ h,
                                                 float* __restrict__ rn, int N) {
    __shared__ float w[H * 516];  // padded rows
    int t = threadIdx.x;
    for (int idx = t; idx < H * F / 4; idx += 256) {
        int f = idx * 4;
        int row = f >> 9;
        int col = f & 511;
        float4 v = *(const float4*)(W1 + f);
        *(float4*)(w + row * 516 + col) = v;
    }
    __syncthreads();

    int j = t & 15, g = t >> 4;
    int i0 = blockIdx.x * 64 + g * 4;

    const float* x0 = x + (size_t)min(i0 + 0, N - 1) * F;
    const float* x1 = x + (size_t)min(i0 + 1, N - 1) * F;
    const float* x2 = x + (size_t)min(i0 + 2, N - 1) * F;
    const float* x3 = x + (size_t)min(i0 + 3, N - 1) * F;
    const float* wr = w + j * 516;

    float acc0 = 0.f, acc1 = 0.f, acc2 = 0.f, acc3 = 0.f;
    for (int k = 0; k < F; k += 4) {
        float4 wv = *(const float4*)(wr + k);
        float4 a = *(const float4*)(x0 + k);
        float4 b = *(const float4*)(x1 + k);
        float4 c = *(const float4*)(x2 + k);
        float4 d = *(const float4*)(x3 + k);
        acc0 += wv.x * a.x + wv.y * a.y + wv.z * a.z + wv.w * a.w;
        acc1 += wv.x * b.x + wv.y * b.y + wv.z * b.z + wv.w * b.w;
        acc2 += wv.x * c.x + wv.y * c.y + wv.z * c.z + wv.w * c.w;
        acc3 += wv.x * d.x + wv.y * d.y + wv.z * d.z + wv.w * d.w;
    }
    float bj = b1[j];
    float accs[4] = {acc0, acc1, acc2, acc3};
    for (int n = 0; n < 4; ++n) {
        int i = i0 + n;
        if (i >= N) break;
        float v = fmaxf(accs[n] + bj, 0.f);
        h[(size_t)i * H + j] = v;
        float sq = v * v;
        sq += __shfl_xor(sq, 1);
        sq += __shfl_xor(sq, 2);
        sq += __shfl_xor(sq, 4);
        sq += __shfl_xor(sq, 8);
        if (j == 0) rn[i] = 1.0f / fmaxf(sqrtf(sq), 1e-12f);
    }
}

// ---------------- AGNN step ----------------
__global__ __launch_bounds__(256) void agnn_step(const float* __restrict__ h,
                                                 const float* __restrict__ rn,
                                                 const int* __restrict__ rp,
                                                 const int* __restrict__ srcs,
                                                 const float* __restrict__ bp,
                                                 float* __restrict__ h_out,
                                                 float* __restrict__ rn_out, int N) {
    int t = threadIdx.x;
    int lane = t & 15, grp = t >> 4;
    int i = blockIdx.x * 16 + grp;
    if (i >= N) return;

    const float L2E = 1.4426950408889634f;
    float beta = bp ? bp[0] : 1.0f;
    float hi = h[(size_t)i * H + lane];
    float rni = rn[i];
    float a = beta * rni * L2E;
    float mm = fabsf(beta) * L2E;

    int e = rp[i], end = rp[i + 1];
    float denom = 0.f, acc = 0.f;

    int s = srcs[e];
    float hs = h[(size_t)s * H + lane];
    float rns = rn[s];
    for (;;) {
        int e2 = e + 1;
        int s2 = 0; float hs2 = 0.f, rns2 = 0.f;
        if (e2 < end) {
            s2 = srcs[e2];
            hs2 = h[(size_t)s2 * H + lane];
            rns2 = rn[s2];
        }
        float p = hi * hs;
        p += __shfl_xor(p, 1);
        p += __shfl_xor(p, 2);
        p += __shfl_xor(p, 4);
        p += __shfl_xor(p, 8);
        float wgt = exp2f(a * rns * p - mm);
        denom += wgt;
        acc = fmaf(wgt, hs, acc);
        if (e2 >= end) break;
        e = e2; s = s2; hs = hs2; rns = rns2;
    }

    float o = acc / denom;
    h_out[(size_t)i * H + lane] = o;
    float sq = o * o;
    sq += __shfl_xor(sq, 1);
    sq += __shfl_xor(sq, 2);
    sq += __shfl_xor(sq, 4);
    sq += __shfl_xor(sq, 8);
    if (lane == 0) rn_out[i] = 1.0f / fmaxf(sqrtf(sq), 1e-12f);
}

// ---------------- head: logits + log_softmax ----------------
__global__ __launch_bounds__(256) void head_kernel(const float* __restrict__ h,
                                                   const float* __restrict__ W2,
                                                   const float* __restrict__ b2,
                                                   float* __restrict__ out, int N) {
    __shared__ float w2[C * H];
    __shared__ float bb[C];
    int t = threadIdx.x;
    if (t < C * H) w2[t] = W2[t];
    if (t < C) bb[t] = b2[t];
    __syncthreads();
    int i = blockIdx.x * blockDim.x + t;
    if (i >= N) return;
    const float4* hp = (const float4*)(h + (size_t)i * H);
    float4 h0 = hp[0], h1 = hp[1], h2 = hp[2], h3 = hp[3];
    float lg[C];
    float m = -1e30f;
    for (int c = 0; c < C; ++c) {
        const float4* wp = (const float4*)(w2 + c * H);
        float4 w0 = wp[0], w1 = wp[1], w2v = wp[2], w3 = wp[3];
        float s = h0.x * w0.x + h0.y * w0.y + h0.z * w0.z + h0.w * w0.w
                + h1.x * w1.x + h1.y * w1.y + h1.z * w1.z + h1.w * w1.w
                + h2.x * w2v.x + h2.y * w2v.y + h2.z * w2v.z + h2.w * w2v.w
                + h3.x * w3.x + h3.y * w3.y + h3.z * w3.z + h3.w * w3.w;
        s += bb[c];
        lg[c] = s;
        m = fmaxf(m, s);
    }
    float sum = 0.f;
    for (int c = 0; c < C; ++c) sum += expf(lg[c] - m);
    float lse = m + logf(sum);
    float* op = out + (size_t)i * C;
    for (int c = 0; c < C; ++c) op[c] = lg[c] - lse;
}

// ---------------- launch ----------------
extern "C" void kernel_launch(void* const* d_in, const int* in_sizes, int n_in,
                              void* d_out, int out_size, void* d_ws, size_t ws_size,
                              hipStream_t stream) {
    const float* x     = (const float*)d_in[0];
    const int*   ei    = (const int*)d_in[1];
    const float* W1    = (const float*)d_in[2];
    const float* b1    = (const float*)d_in[3];
    const float* beta2 = (const float*)d_in[4];
    const float* beta3 = (const float*)d_in[5];
    const float* beta4 = (const float*)d_in[6];
    const float* W2    = (const float*)d_in[7];
    const float* b2    = (const float*)d_in[8];
    float* out = (float*)d_out;

    int N = in_sizes[0] / F;     // 100000
    int E = in_sizes[1] / 2;     // 3200000
    int Etot = E + N;
    int width = (N + NB - 1) / NB;   // 196

    char* p = (char*)d_ws;
    float* h_a   = (float*)p; p += (size_t)N * H * 4;
    float* h_b   = (float*)p; p += (size_t)N * H * 4;
    float* rn_a  = (float*)p; p += (size_t)N * 4;
    float* rn_b  = (float*)p; p += (size_t)N * 4;
    int* rp      = (int*)p;   p += (size_t)(N + 1) * 4;
    int* srcs    = (int*)p;   p += (size_t)Etot * 4;
    unsigned* binned = (unsigned*)p; p += (size_t)Etot * 4;
    int* gcnt    = (int*)p;   p += (size_t)NB * 4;
    int* bbase   = (int*)p;   p += (size_t)(NB + 1) * 4;
    int* gcur    = (int*)p;   p += (size_t)NB * 4;

    // CSR build (two-level binned counting sort)
    zero_i32<<<(NB + 255) / 256, 256, 0, stream>>>(gcnt, NB);
    bucket_hist<<<1024, 256, 0, stream>>>(ei, E, Etot, width, gcnt);
    bucket_scan<<<1, NB, 0, stream>>>(gcnt, Etot, bbase, gcur, rp, N);
    bin_edges<<<(Etot + BIN_CHUNK - 1) / BIN_CHUNK, 256, 0, stream>>>(ei, E, Etot, width, gcur, binned);
    bucket_sort<<<NB, 256, 0, stream>>>(binned, bbase, width, N, rp, srcs);

    // lin1 + initial norms
    lin1_relu<<<(N + 63) / 64, 256, 0, stream>>>(x, W1, b1, h_a, rn_a, N);

    // 4 AGNN steps (beta1 fixed at 1.0 -> nullptr)
    int gs = (N + 15) / 16;
    agnn_step<<<gs, 256, 0, stream>>>(h_a, rn_a, rp, srcs, nullptr, h_b, rn_b, N);
    agnn_step<<<gs, 256, 0, stream>>>(h_b, rn_b, rp, srcs, beta2, h_a, rn_a, N);
    agnn_step<<<gs, 256, 0, stream>>>(h_a, rn_a, rp, srcs, beta3, h_b, rn_b, N);
    agnn_step<<<gs, 256, 0, stream>>>(h_b, rn_b, rp, srcs, beta4, h_a, rn_a, N);

    // head
    head_kernel<<<(N + 255) / 256, 256, 0, stream>>>(h_a, W2, b2, out, N);
}

// Round 3
// 876.851 us; speedup vs baseline: 1.4572x; 1.1568x over previous
//
#include <hip/hip_runtime.h>
#include <math.h>

#define F 512
#define H 16
#define C 7
#define NB 512          // coarse buckets for CSR build
#define BIN_CHUNK 4096  // edges per block in bin_edges

// ---------------- utility ----------------
__global__ void zero_i32(int* p, int n) {
    int i = blockIdx.x * blockDim.x + threadIdx.x;
    if (i < n) p[i] = 0;
}

// ---------------- CSR build: two-level LDS-binned counting sort ----------------
__global__ __launch_bounds__(256) void bucket_hist(const int* __restrict__ ei, int E, int Etot,
                                                   int width, int* __restrict__ gcnt) {
    __shared__ int h[NB];
    for (int i = threadIdx.x; i < NB; i += 256) h[i] = 0;
    __syncthreads();
    int stride = gridDim.x * 256;
    for (int e = blockIdx.x * 256 + threadIdx.x; e < Etot; e += stride) {
        int dst = (e < E) ? ei[E + e] : (e - E);
        atomicAdd(&h[dst / width], 1);
    }
    __syncthreads();
    for (int i = threadIdx.x; i < NB; i += 256)
        if (h[i]) atomicAdd(&gcnt[i], h[i]);
}

__global__ void bucket_scan(const int* __restrict__ gcnt, int Etot,
                            int* __restrict__ bbase, int* __restrict__ gcur,
                            int* __restrict__ rp, int N) {
    __shared__ int s[NB];
    int t = threadIdx.x;
    int own = gcnt[t];
    s[t] = own;
    __syncthreads();
    for (int d = 1; d < NB; d <<= 1) {
        int add = (t >= d) ? s[t - d] : 0;
        __syncthreads();
        s[t] += add;
        __syncthreads();
    }
    int excl = s[t] - own;
    bbase[t] = excl;
    gcur[t] = excl;
    if (t == NB - 1) bbase[NB] = s[t];
    if (t == 0) rp[N] = Etot;
}

__global__ __launch_bounds__(256) void bin_edges(const int* __restrict__ ei, int E, int Etot,
                                                 int width, int* __restrict__ gcur,
                                                 unsigned* __restrict__ binned) {
    __shared__ int cnt[NB];
    __shared__ int base[NB];
    int t = threadIdx.x;
    for (int i = t; i < NB; i += 256) cnt[i] = 0;
    __syncthreads();
    long chunk0 = (long)blockIdx.x * BIN_CHUNK;
    for (int k = 0; k < BIN_CHUNK / 256; ++k) {
        long e = chunk0 + k * 256 + t;
        if (e < Etot) {
            int dst = (e < E) ? ei[E + e] : (int)(e - E);
            atomicAdd(&cnt[dst / width], 1);
        }
    }
    __syncthreads();
    for (int i = t; i < NB; i += 256) {
        int c = cnt[i];
        base[i] = c ? atomicAdd(&gcur[i], c) : 0;
        cnt[i] = 0;
    }
    __syncthreads();
    for (int k = 0; k < BIN_CHUNK / 256; ++k) {
        long e = chunk0 + k * 256 + t;
        if (e < Etot) {
            int src, dst;
            if (e < E) { src = ei[e]; dst = ei[E + e]; }
            else       { src = (int)(e - E); dst = src; }
            int b = dst / width;
            int pos = base[b] + atomicAdd(&cnt[b], 1);
            binned[pos] = (unsigned)src | ((unsigned)(dst - b * width) << 17);
        }
    }
}

__global__ __launch_bounds__(256) void bucket_sort(const unsigned* __restrict__ binned,
                                                   const int* __restrict__ bbase,
                                                   int width, int N,
                                                   int* __restrict__ rp, int* __restrict__ srcs) {
    __shared__ int cnt[256];
    __shared__ int cur[256];
    int b = blockIdx.x, t = threadIdx.x;
    int r0 = bbase[b], r1 = bbase[b + 1];
    int nodeBase = b * width;
    cnt[t] = 0;
    cur[t] = 0;
    __syncthreads();
    for (int e = r0 + t; e < r1; e += 256) {
        unsigned p = binned[e];
        atomicAdd(&cnt[p >> 17], 1);
    }
    __syncthreads();
    int own = cnt[t];
    for (int d = 1; d < 256; d <<= 1) {
        int add = (t >= d) ? cnt[t - d] : 0;
        __syncthreads();
        cnt[t] += add;
        __syncthreads();
    }
    int excl = cnt[t] - own;
    int node = nodeBase + t;
    if (t < width && node < N) rp[node] = r0 + excl;
    __syncthreads();
    cnt[t] = excl;
    __syncthreads();
    for (int e = r0 + t; e < r1; e += 256) {
        unsigned p = binned[e];
        int dL = p >> 17;
        int pos = r0 + cnt[dL] + atomicAdd(&cur[dL], 1);
        srcs[pos] = (int)(p & 0x1FFFFu);
    }
}

// ---------------- lin1 v2: split-K, contiguous per-lane x loads ----------------
// Block 256 = 32 nodes. Thread (s = t&15 k-slice, g = t>>4): nodes iA = base+g, iB = iA+16.
// Each thread reads 2 x-chunks of 128 B (contiguous) and partial-dots all 16 outputs.
__global__ __launch_bounds__(256) void lin1_relu(const float* __restrict__ x,
                                                 const float* __restrict__ W1,
                                                 const float* __restrict__ b1,
                                                 float* __restrict__ h,
                                                 float* __restrict__ rn, int N) {
    __shared__ float4 w4[16 * 16 * 9];  // [j][s][m], slice stride 9 float4 -> 2-way banks only
    int t = threadIdx.x;
    for (int r = 0; r < 8; ++r) {
        int idx = r * 256 + t;            // [0, 2048)
        int j = idx >> 7;
        int rem = idx & 127;
        int s = rem >> 3, m = rem & 7;
        w4[(j * 16 + s) * 9 + m] = ((const float4*)W1)[idx];
    }
    __syncthreads();

    int s = t & 15, g = t >> 4;
    int iA = blockIdx.x * 32 + g;
    int iB = iA + 16;
    int iAc = min(iA, N - 1), iBc = min(iB, N - 1);

    const float4* xA4 = (const float4*)(x + (size_t)iAc * F);
    const float4* xB4 = (const float4*)(x + (size_t)iBc * F);
    float4 xa[8], xb[8];
#pragma unroll
    for (int m = 0; m < 8; ++m) xa[m] = xA4[s * 8 + m];
#pragma unroll
    for (int m = 0; m < 8; ++m) xb[m] = xB4[s * 8 + m];

    float vA[16], vB[16];
#pragma unroll
    for (int j = 0; j < 16; ++j) { vA[j] = 0.f; vB[j] = 0.f; }
#pragma unroll
    for (int j = 0; j < 16; ++j) {
        const float4* wr = &w4[(j * 16 + s) * 9];
#pragma unroll
        for (int m = 0; m < 8; ++m) {
            float4 w = wr[m];
            vA[j] += w.x * xa[m].x + w.y * xa[m].y + w.z * xa[m].z + w.w * xa[m].w;
            vB[j] += w.x * xb[m].x + w.y * xb[m].y + w.z * xb[m].z + w.w * xb[m].w;
        }
    }

    // 4-stage halving exchange across the 16 k-slices: lane s ends with full sum for j=s
#pragma unroll
    for (int st = 0; st < 4; ++st) {
        int bit = (s >> st) & 1;
        int cntj = 16 >> (st + 1);
#pragma unroll
        for (int k = 0; k < 8; ++k) {
            if (k < cntj) {
                float keepA = bit ? vA[2 * k + 1] : vA[2 * k];
                float giveA = bit ? vA[2 * k] : vA[2 * k + 1];
                vA[k] = keepA + __shfl_xor(giveA, 1 << st);
                float keepB = bit ? vB[2 * k + 1] : vB[2 * k];
                float giveB = bit ? vB[2 * k] : vB[2 * k + 1];
                vB[k] = keepB + __shfl_xor(giveB, 1 << st);
            }
        }
    }

    float bs = b1[s];
    float oA = fmaxf(vA[0] + bs, 0.f);
    float oB = fmaxf(vB[0] + bs, 0.f);
    if (iA < N) h[(size_t)iA * H + s] = oA;
    if (iB < N) h[(size_t)iB * H + s] = oB;

    float sqA = oA * oA, sqB = oB * oB;
    sqA += __shfl_xor(sqA, 1); sqA += __shfl_xor(sqA, 2);
    sqA += __shfl_xor(sqA, 4); sqA += __shfl_xor(sqA, 8);
    sqB += __shfl_xor(sqB, 1); sqB += __shfl_xor(sqB, 2);
    sqB += __shfl_xor(sqB, 4); sqB += __shfl_xor(sqB, 8);
    if (s == 0) {
        if (iA < N) rn[iA] = 1.0f / fmaxf(sqrtf(sqA), 1e-12f);
        if (iB < N) rn[iB] = 1.0f / fmaxf(sqrtf(sqB), 1e-12f);
    }
}

// ---------------- AGNN step v2: 1 wave per dst, 4 edges per iteration ----------------
// lane = (q = lane>>4 edge sub-lane, f = lane&15 feature). Prefetch one iteration ahead.
__global__ __launch_bounds__(256) void agnn_step(const float* __restrict__ h,
                                                 const float* __restrict__ rn,
                                                 const int* __restrict__ rp,
                                                 const int* __restrict__ srcs,
                                                 const float* __restrict__ bp,
                                                 float* __restrict__ h_out,
                                                 float* __restrict__ rn_out, int N) {
    int t = threadIdx.x;
    int wave = t >> 6, lane = t & 63;
    int f = lane & 15, q = lane >> 4;
    int i = blockIdx.x * 4 + wave;
    if (i >= N) return;

    const float L2E = 1.4426950408889634f;
    float beta = bp ? bp[0] : 1.0f;
    float hi = h[(size_t)i * H + f];
    float rni = rn[i];
    float aL = beta * rni * L2E;
    float mm = fabsf(beta) * L2E;

    int e0 = rp[i], end = rp[i + 1];
    float denom = 0.f, acc = 0.f;

    // prefetch first quad
    int eq = e0 + q;
    bool vA = eq < end;
    int sA = srcs[vA ? eq : end - 1];
    float hsA = h[(size_t)sA * H + f];
    float rnA = rn[sA];

    for (int base = e0;; base += 4) {
        int nbase = base + 4;
        bool anyNext = nbase < end;   // wave-uniform
        int sB = 0; float hsB = 0.f, rnB = 0.f; bool vB = false;
        if (anyNext) {
            int eqn = nbase + q;
            vB = eqn < end;
            sB = srcs[vB ? eqn : end - 1];
            hsB = h[(size_t)sB * H + f];
            rnB = rn[sB];
        }
        float p = hi * hsA;
        p += __shfl_xor(p, 1);
        p += __shfl_xor(p, 2);
        p += __shfl_xor(p, 4);
        p += __shfl_xor(p, 8);
        float wgt = exp2f(aL * rnA * p - mm);
        wgt = vA ? wgt : 0.f;
        denom += wgt;
        acc = fmaf(wgt, hsA, acc);
        if (!anyNext) break;
        sA = sB; hsA = hsB; rnA = rnB; vA = vB;
    }

    // combine the 4 edge sub-lanes
    acc += __shfl_xor(acc, 16);
    acc += __shfl_xor(acc, 32);
    denom += __shfl_xor(denom, 16);
    denom += __shfl_xor(denom, 32);

    float o = acc / denom;
    if (q == 0) h_out[(size_t)i * H + f] = o;
    float sq = o * o;
    sq += __shfl_xor(sq, 1);
    sq += __shfl_xor(sq, 2);
    sq += __shfl_xor(sq, 4);
    sq += __shfl_xor(sq, 8);
    if (lane == 0) rn_out[i] = 1.0f / fmaxf(sqrtf(sq), 1e-12f);
}

// ---------------- head: logits + log_softmax ----------------
__global__ __launch_bounds__(256) void head_kernel(const float* __restrict__ h,
                                                   const float* __restrict__ W2,
                                                   const float* __restrict__ b2,
                                                   float* __restrict__ out, int N) {
    __shared__ float w2[C * H];
    __shared__ float bb[C];
    int t = threadIdx.x;
    if (t < C * H) w2[t] = W2[t];
    if (t < C) bb[t] = b2[t];
    __syncthreads();
    int i = blockIdx.x * blockDim.x + t;
    if (i >= N) return;
    const float4* hp = (const float4*)(h + (size_t)i * H);
    float4 h0 = hp[0], h1 = hp[1], h2 = hp[2], h3 = hp[3];
    float lg[C];
    float m = -1e30f;
    for (int c = 0; c < C; ++c) {
        const float4* wp = (const float4*)(w2 + c * H);
        float4 w0 = wp[0], w1 = wp[1], w2v = wp[2], w3 = wp[3];
        float s = h0.x * w0.x + h0.y * w0.y + h0.z * w0.z + h0.w * w0.w
                + h1.x * w1.x + h1.y * w1.y + h1.z * w1.z + h1.w * w1.w
                + h2.x * w2v.x + h2.y * w2v.y + h2.z * w2v.z + h2.w * w2v.w
                + h3.x * w3.x + h3.y * w3.y + h3.z * w3.z + h3.w * w3.w;
        s += bb[c];
        lg[c] = s;
        m = fmaxf(m, s);
    }
    float sum = 0.f;
    for (int c = 0; c < C; ++c) sum += expf(lg[c] - m);
    float lse = m + logf(sum);
    float* op = out + (size_t)i * C;
    for (int c = 0; c < C; ++c) op[c] = lg[c] - lse;
}

// ---------------- launch ----------------
extern "C" void kernel_launch(void* const* d_in, const int* in_sizes, int n_in,
                              void* d_out, int out_size, void* d_ws, size_t ws_size,
                              hipStream_t stream) {
    const float* x     = (const float*)d_in[0];
    const int*   ei    = (const int*)d_in[1];
    const float* W1    = (const float*)d_in[2];
    const float* b1    = (const float*)d_in[3];
    const float* beta2 = (const float*)d_in[4];
    const float* beta3 = (const float*)d_in[5];
    const float* beta4 = (const float*)d_in[6];
    const float* W2    = (const float*)d_in[7];
    const float* b2    = (const float*)d_in[8];
    float* out = (float*)d_out;

    int N = in_sizes[0] / F;     // 100000
    int E = in_sizes[1] / 2;     // 3200000
    int Etot = E + N;
    int width = (N + NB - 1) / NB;   // 196

    char* p = (char*)d_ws;
    float* h_a   = (float*)p; p += (size_t)N * H * 4;
    float* h_b   = (float*)p; p += (size_t)N * H * 4;
    float* rn_a  = (float*)p; p += (size_t)N * 4;
    float* rn_b  = (float*)p; p += (size_t)N * 4;
    int* rp      = (int*)p;   p += (size_t)(N + 1) * 4;
    int* srcs    = (int*)p;   p += (size_t)Etot * 4;
    unsigned* binned = (unsigned*)p; p += (size_t)Etot * 4;
    int* gcnt    = (int*)p;   p += (size_t)NB * 4;
    int* bbase   = (int*)p;   p += (size_t)(NB + 1) * 4;
    int* gcur    = (int*)p;   p += (size_t)NB * 4;

    // CSR build
    zero_i32<<<(NB + 255) / 256, 256, 0, stream>>>(gcnt, NB);
    bucket_hist<<<1024, 256, 0, stream>>>(ei, E, Etot, width, gcnt);
    bucket_scan<<<1, NB, 0, stream>>>(gcnt, Etot, bbase, gcur, rp, N);
    bin_edges<<<(Etot + BIN_CHUNK - 1) / BIN_CHUNK, 256, 0, stream>>>(ei, E, Etot, width, gcur, binned);
    bucket_sort<<<NB, 256, 0, stream>>>(binned, bbase, width, N, rp, srcs);

    // lin1 + initial norms
    lin1_relu<<<(N + 31) / 32, 256, 0, stream>>>(x, W1, b1, h_a, rn_a, N);

    // 4 AGNN steps
    int gs = (N + 3) / 4;
    agnn_step<<<gs, 256, 0, stream>>>(h_a, rn_a, rp, srcs, nullptr, h_b, rn_b, N);
    agnn_step<<<gs, 256, 0, stream>>>(h_b, rn_b, rp, srcs, beta2, h_a, rn_a, N);
    agnn_step<<<gs, 256, 0, stream>>>(h_a, rn_a, rp, srcs, beta3, h_b, rn_b, N);
    agnn_step<<<gs, 256, 0, stream>>>(h_b, rn_b, rp, srcs, beta4, h_a, rn_a, N);

    // head
    head_kernel<<<(N + 255) / 256, 256, 0, stream>>>(h_a, W2, b2, out, N);
}

// Round 4
// 715.324 us; speedup vs baseline: 1.7862x; 1.2258x over previous
//
#include <hip/hip_runtime.h>
#include <hip/hip_fp16.h>
#include <math.h>

#define F 512
#define H 16
#define C 7
#define NB 512          // coarse buckets for CSR build
#define BIN_CHUNK 4096  // edges per block in bin_edges

// ---------------- utility ----------------
__global__ void zero_i32(int* p, int n) {
    int i = blockIdx.x * blockDim.x + threadIdx.x;
    if (i < n) p[i] = 0;
}

// ---------------- CSR build v2: 3 kernels, fixed-capacity buckets ----------------
// K1: bin edges directly into per-bucket regions of capacity `cap`.
//     packed word = src | (dstLocal << 17)  (src < 2^17, dstLocal < 2^15)
__global__ __launch_bounds__(256) void bin_edges(const int* __restrict__ ei, int E, int Etot,
                                                 int width, int cap, int* __restrict__ gcnt,
                                                 unsigned* __restrict__ binned) {
    __shared__ int cnt[NB];
    __shared__ int base[NB];
    int t = threadIdx.x;
    for (int i = t; i < NB; i += 256) cnt[i] = 0;
    __syncthreads();
    long chunk0 = (long)blockIdx.x * BIN_CHUNK;
    for (int k = 0; k < BIN_CHUNK / 256; ++k) {
        long e = chunk0 + k * 256 + t;
        if (e < Etot) {
            int dst = (e < E) ? ei[E + e] : (int)(e - E);
            atomicAdd(&cnt[dst / width], 1);
        }
    }
    __syncthreads();
    for (int i = t; i < NB; i += 256) {
        int c = cnt[i];
        base[i] = c ? atomicAdd(&gcnt[i], c) : 0;
        cnt[i] = 0;
    }
    __syncthreads();
    for (int k = 0; k < BIN_CHUNK / 256; ++k) {
        long e = chunk0 + k * 256 + t;
        if (e < Etot) {
            int src, dst;
            if (e < E) { src = ei[e]; dst = ei[E + e]; }
            else       { src = (int)(e - E); dst = src; }
            int b = dst / width;
            size_t pos = (size_t)b * cap + base[b] + atomicAdd(&cnt[b], 1);
            binned[pos] = (unsigned)src | ((unsigned)(dst - b * width) << 17);
        }
    }
}

// K2: exclusive scan of bucket counts -> bbase
__global__ void bucket_scan(const int* __restrict__ gcnt, int Etot,
                            int* __restrict__ bbase, int* __restrict__ rp, int N) {
    __shared__ int s[NB];
    int t = threadIdx.x;
    int own = gcnt[t];
    s[t] = own;
    __syncthreads();
    for (int d = 1; d < NB; d <<= 1) {
        int add = (t >= d) ? s[t - d] : 0;
        __syncthreads();
        s[t] += add;
        __syncthreads();
    }
    bbase[t] = s[t] - own;
    if (t == NB - 1) bbase[NB] = s[t];
    if (t == 0) rp[N] = Etot;
}

// K3: per-bucket counting sort -> rp + srcs (scatter confined to ~26 KB region)
__global__ __launch_bounds__(256) void bucket_sort(const unsigned* __restrict__ binned,
                                                   const int* __restrict__ gcnt,
                                                   const int* __restrict__ bbase,
                                                   int width, int cap, int N,
                                                   int* __restrict__ rp, int* __restrict__ srcs) {
    __shared__ int cnt[256];
    __shared__ int cur[256];
    int b = blockIdx.x, t = threadIdx.x;
    int r0 = bbase[b];
    int ne = gcnt[b];
    const unsigned* bin = binned + (size_t)b * cap;
    int nodeBase = b * width;
    cnt[t] = 0;
    cur[t] = 0;
    __syncthreads();
    for (int e = t; e < ne; e += 256) {
        atomicAdd(&cnt[bin[e] >> 17], 1);
    }
    __syncthreads();
    int own = cnt[t];
    for (int d = 1; d < 256; d <<= 1) {
        int add = (t >= d) ? cnt[t - d] : 0;
        __syncthreads();
        cnt[t] += add;
        __syncthreads();
    }
    int excl = cnt[t] - own;
    int node = nodeBase + t;
    if (t < width && node < N) rp[node] = r0 + excl;
    __syncthreads();
    cnt[t] = excl;
    __syncthreads();
    for (int e = t; e < ne; e += 256) {
        unsigned p = bin[e];
        int dL = p >> 17;
        int pos = r0 + cnt[dL] + atomicAdd(&cur[dL], 1);
        srcs[pos] = (int)(p & 0x1FFFFu);
    }
}

// ---------------- lin1: h = relu(x@W1^T+b1); store hn = h/||h|| (fp16) + nm = ||h|| (fp32) ----------------
__global__ __launch_bounds__(256) void lin1_relu(const float* __restrict__ x,
                                                 const float* __restrict__ W1,
                                                 const float* __restrict__ b1,
                                                 __half* __restrict__ hn,
                                                 float* __restrict__ nm, int N) {
    __shared__ float4 w4[16 * 16 * 9];  // [j][s][m], slice stride 9 float4
    int t = threadIdx.x;
    for (int r = 0; r < 8; ++r) {
        int idx = r * 256 + t;
        int j = idx >> 7;
        int rem = idx & 127;
        int s = rem >> 3, m = rem & 7;
        w4[(j * 16 + s) * 9 + m] = ((const float4*)W1)[idx];
    }
    __syncthreads();

    int s = t & 15, g = t >> 4;
    int iA = blockIdx.x * 32 + g;
    int iB = iA + 16;
    int iAc = min(iA, N - 1), iBc = min(iB, N - 1);

    const float4* xA4 = (const float4*)(x + (size_t)iAc * F);
    const float4* xB4 = (const float4*)(x + (size_t)iBc * F);
    float4 xa[8], xb[8];
#pragma unroll
    for (int m = 0; m < 8; ++m) xa[m] = xA4[s * 8 + m];
#pragma unroll
    for (int m = 0; m < 8; ++m) xb[m] = xB4[s * 8 + m];

    float vA[16], vB[16];
#pragma unroll
    for (int j = 0; j < 16; ++j) { vA[j] = 0.f; vB[j] = 0.f; }
#pragma unroll
    for (int j = 0; j < 16; ++j) {
        const float4* wr = &w4[(j * 16 + s) * 9];
#pragma unroll
        for (int m = 0; m < 8; ++m) {
            float4 w = wr[m];
            vA[j] += w.x * xa[m].x + w.y * xa[m].y + w.z * xa[m].z + w.w * xa[m].w;
            vB[j] += w.x * xb[m].x + w.y * xb[m].y + w.z * xb[m].z + w.w * xb[m].w;
        }
    }

#pragma unroll
    for (int st = 0; st < 4; ++st) {
        int bit = (s >> st) & 1;
        int cntj = 16 >> (st + 1);
#pragma unroll
        for (int k = 0; k < 8; ++k) {
            if (k < cntj) {
                float keepA = bit ? vA[2 * k + 1] : vA[2 * k];
                float giveA = bit ? vA[2 * k] : vA[2 * k + 1];
                vA[k] = keepA + __shfl_xor(giveA, 1 << st);
                float keepB = bit ? vB[2 * k + 1] : vB[2 * k];
                float giveB = bit ? vB[2 * k] : vB[2 * k + 1];
                vB[k] = keepB + __shfl_xor(giveB, 1 << st);
            }
        }
    }

    float bs = b1[s];
    float oA = fmaxf(vA[0] + bs, 0.f);
    float oB = fmaxf(vB[0] + bs, 0.f);

    float sqA = oA * oA, sqB = oB * oB;
    sqA += __shfl_xor(sqA, 1); sqA += __shfl_xor(sqA, 2);
    sqA += __shfl_xor(sqA, 4); sqA += __shfl_xor(sqA, 8);
    sqB += __shfl_xor(sqB, 1); sqB += __shfl_xor(sqB, 2);
    sqB += __shfl_xor(sqB, 4); sqB += __shfl_xor(sqB, 8);
    float nmA = sqrtf(sqA), nmB = sqrtf(sqB);
    float rnA = 1.0f / fmaxf(nmA, 1e-12f);
    float rnB = 1.0f / fmaxf(nmB, 1e-12f);

    if (iA < N) {
        hn[(size_t)iA * H + s] = __float2half(oA * rnA);
        if (s == 0) nm[iA] = nmA;
    }
    if (iB < N) {
        hn[(size_t)iB * H + s] = __float2half(oB * rnB);
        if (s == 0) nm[iB] = nmB;
    }
}

// ---------------- AGNN step v3: fp16 normalized rows, 8 edges/iter, 8-ahead prefetch ----------------
// wave per dst; lane = (q = lane>>4, f = lane&15); lane handles edges base+q and base+4+q.
__global__ __launch_bounds__(256) void agnn_step(const __half* __restrict__ hn,
                                                 const float* __restrict__ nm,
                                                 const int* __restrict__ rp,
                                                 const int* __restrict__ srcs,
                                                 const float* __restrict__ bp,
                                                 __half* __restrict__ hn_out,
                                                 float* __restrict__ nm_out, int N) {
    int t = threadIdx.x;
    int wave = t >> 6, lane = t & 63;
    int f = lane & 15, q = lane >> 4;
    int i = blockIdx.x * 4 + wave;
    if (i >= N) return;

    const float L2E = 1.4426950408889634f;
    float beta = bp ? bp[0] : 1.0f;
    float hi = __half2float(hn[(size_t)i * H + f]);
    float aL = beta * L2E;
    float mm = fabsf(beta) * L2E;

    int e0 = rp[i], end = rp[i + 1];
    float denom = 0.f, acc = 0.f;

    int eA = e0 + q, eB = e0 + 4 + q;
    bool vA = eA < end, vB = eB < end;
    int sA = srcs[vA ? eA : e0];
    int sB = srcs[vB ? eB : e0];
    float hsA = __half2float(hn[(size_t)sA * H + f]);
    float hsB = __half2float(hn[(size_t)sB * H + f]);
    float nmA = nm[sA], nmB = nm[sB];

    for (int base = e0;; base += 8) {
        int nb = base + 8;
        bool anyNext = nb < end;   // wave-uniform
        int sA2 = 0, sB2 = 0; float hsA2 = 0.f, hsB2 = 0.f, nmA2 = 0.f, nmB2 = 0.f;
        bool vA2 = false, vB2 = false;
        if (anyNext) {
            int eA2 = nb + q, eB2 = nb + 4 + q;
            vA2 = eA2 < end; vB2 = eB2 < end;
            sA2 = srcs[vA2 ? eA2 : e0];
            sB2 = srcs[vB2 ? eB2 : e0];
            hsA2 = __half2float(hn[(size_t)sA2 * H + f]);
            hsB2 = __half2float(hn[(size_t)sB2 * H + f]);
            nmA2 = nm[sA2]; nmB2 = nm[sB2];
        }
        float pA = hi * hsA, pB = hi * hsB;
        pA += __shfl_xor(pA, 1); pB += __shfl_xor(pB, 1);
        pA += __shfl_xor(pA, 2); pB += __shfl_xor(pB, 2);
        pA += __shfl_xor(pA, 4); pB += __shfl_xor(pB, 4);
        pA += __shfl_xor(pA, 8); pB += __shfl_xor(pB, 8);
        float wA = exp2f(fmaf(aL, pA, -mm));
        float wB = exp2f(fmaf(aL, pB, -mm));
        wA = vA ? wA : 0.f;
        wB = vB ? wB : 0.f;
        denom += wA + wB;
        acc = fmaf(wA * nmA, hsA, acc);
        acc = fmaf(wB * nmB, hsB, acc);
        if (!anyNext) break;
        sA = sA2; sB = sB2; hsA = hsA2; hsB = hsB2; nmA = nmA2; nmB = nmB2;
        vA = vA2; vB = vB2;
    }

    acc += __shfl_xor(acc, 16);
    acc += __shfl_xor(acc, 32);
    denom += __shfl_xor(denom, 16);
    denom += __shfl_xor(denom, 32);

    float o = acc / denom;
    float sq = o * o;
    sq += __shfl_xor(sq, 1);
    sq += __shfl_xor(sq, 2);
    sq += __shfl_xor(sq, 4);
    sq += __shfl_xor(sq, 8);
    float nmo = sqrtf(sq);
    float rno = 1.0f / fmaxf(nmo, 1e-12f);
    if (lane < 16) {
        hn_out[(size_t)i * H + f] = __float2half(o * rno);
        if (f == 0) nm_out[i] = nmo;
    }
}

// ---------------- head: logits + log_softmax (reads hn*nm) ----------------
__global__ __launch_bounds__(256) void head_kernel(const __half* __restrict__ hn,
                                                   const float* __restrict__ nm,
                                                   const float* __restrict__ W2,
                                                   const float* __restrict__ b2,
                                                   float* __restrict__ out, int N) {
    __shared__ float w2[C * H];
    __shared__ float bb[C];
    int t = threadIdx.x;
    if (t < C * H) w2[t] = W2[t];
    if (t < C) bb[t] = b2[t];
    __syncthreads();
    int i = blockIdx.x * blockDim.x + t;
    if (i >= N) return;
    float nmi = nm[i];
    const __half2* hp = (const __half2*)(hn + (size_t)i * H);
    float hv[H];
#pragma unroll
    for (int k = 0; k < 8; ++k) {
        float2 v = __half22float2(hp[k]);
        hv[2 * k] = v.x * nmi;
        hv[2 * k + 1] = v.y * nmi;
    }
    float lg[C];
    float m = -1e30f;
#pragma unroll
    for (int c = 0; c < C; ++c) {
        float s = bb[c];
#pragma unroll
        for (int k = 0; k < H; ++k) s += hv[k] * w2[c * H + k];
        lg[c] = s;
        m = fmaxf(m, s);
    }
    float sum = 0.f;
#pragma unroll
    for (int c = 0; c < C; ++c) sum += expf(lg[c] - m);
    float lse = m + logf(sum);
    float* op = out + (size_t)i * C;
#pragma unroll
    for (int c = 0; c < C; ++c) op[c] = lg[c] - lse;
}

// ---------------- launch ----------------
extern "C" void kernel_launch(void* const* d_in, const int* in_sizes, int n_in,
                              void* d_out, int out_size, void* d_ws, size_t ws_size,
                              hipStream_t stream) {
    const float* x     = (const float*)d_in[0];
    const int*   ei    = (const int*)d_in[1];
    const float* W1    = (const float*)d_in[2];
    const float* b1    = (const float*)d_in[3];
    const float* beta2 = (const float*)d_in[4];
    const float* beta3 = (const float*)d_in[5];
    const float* beta4 = (const float*)d_in[6];
    const float* W2    = (const float*)d_in[7];
    const float* b2    = (const float*)d_in[8];
    float* out = (float*)d_out;

    int N = in_sizes[0] / F;     // 100000
    int E = in_sizes[1] / 2;     // 3200000
    int Etot = E + N;
    int width = (N + NB - 1) / NB;   // 196
    int cap = (Etot / NB) * 2;       // 2x mean bucket size (~22 sigma margin)

    char* p = (char*)d_ws;
    __half* hn_a = (__half*)p; p += (size_t)N * H * 2;
    __half* hn_b = (__half*)p; p += (size_t)N * H * 2;
    float* nm_a  = (float*)p;  p += (size_t)N * 4;
    float* nm_b  = (float*)p;  p += (size_t)N * 4;
    int* rp      = (int*)p;    p += (size_t)(N + 1) * 4;
    int* srcs    = (int*)p;    p += (size_t)Etot * 4;
    int* gcnt    = (int*)p;    p += (size_t)NB * 4;
    int* bbase   = (int*)p;    p += (size_t)(NB + 1) * 4;
    p = (char*)(((size_t)p + 255) & ~(size_t)255);
    unsigned* binned = (unsigned*)p; p += (size_t)NB * cap * 4;

    // CSR build (3 kernels)
    zero_i32<<<(NB + 255) / 256, 256, 0, stream>>>(gcnt, NB);
    bin_edges<<<(Etot + BIN_CHUNK - 1) / BIN_CHUNK, 256, 0, stream>>>(ei, E, Etot, width, cap, gcnt, binned);
    bucket_scan<<<1, NB, 0, stream>>>(gcnt, Etot, bbase, rp, N);
    bucket_sort<<<NB, 256, 0, stream>>>(binned, gcnt, bbase, width, cap, N, rp, srcs);

    // lin1 + initial normalized rows
    lin1_relu<<<(N + 31) / 32, 256, 0, stream>>>(x, W1, b1, hn_a, nm_a, N);

    // 4 AGNN steps
    int gs = (N + 3) / 4;
    agnn_step<<<gs, 256, 0, stream>>>(hn_a, nm_a, rp, srcs, nullptr, hn_b, nm_b, N);
    agnn_step<<<gs, 256, 0, stream>>>(hn_b, nm_b, rp, srcs, beta2, hn_a, nm_a, N);
    agnn_step<<<gs, 256, 0, stream>>>(hn_a, nm_a, rp, srcs, beta3, hn_b, nm_b, N);
    agnn_step<<<gs, 256, 0, stream>>>(hn_b, nm_b, rp, srcs, beta4, hn_a, nm_a, N);

    // head
    head_kernel<<<(N + 255) / 256, 256, 0, stream>>>(hn_a, nm_a, W2, b2, out, N);
}

// Round 5
// 656.847 us; speedup vs baseline: 1.9452x; 1.0890x over previous
//
#include <hip/hip_runtime.h>
#include <hip/hip_fp16.h>
#include <math.h>

#define F 512
#define H 16
#define C 7
#define NB 512          // coarse buckets for CSR build
#define BIN_CHUNK 4096  // edges per block in bin_edges

typedef _Float16 h2 __attribute__((ext_vector_type(2)));

__device__ __forceinline__ h2 as_h2(unsigned u) { return __builtin_bit_cast(h2, u); }
__device__ __forceinline__ unsigned as_u32(h2 v) { return __builtin_bit_cast(unsigned, v); }

__device__ __forceinline__ float dot2acc(h2 a, h2 b, float c) {
#if __has_builtin(__builtin_amdgcn_fdot2)
    return __builtin_amdgcn_fdot2(a, b, c, false);
#else
    return c + (float)a[0] * (float)b[0] + (float)a[1] * (float)b[1];
#endif
}

// ---------------- utility ----------------
__global__ void zero_i32(int* p, int n) {
    int i = blockIdx.x * blockDim.x + threadIdx.x;
    if (i < n) p[i] = 0;
}

// ---------------- CSR build: 3 kernels, fixed-capacity buckets ----------------
__global__ __launch_bounds__(256) void bin_edges(const int* __restrict__ ei, int E, int Etot,
                                                 int width, int cap, int* __restrict__ gcnt,
                                                 unsigned* __restrict__ binned) {
    __shared__ int cnt[NB];
    __shared__ int base[NB];
    int t = threadIdx.x;
    for (int i = t; i < NB; i += 256) cnt[i] = 0;
    __syncthreads();
    long chunk0 = (long)blockIdx.x * BIN_CHUNK;
    for (int k = 0; k < BIN_CHUNK / 256; ++k) {
        long e = chunk0 + k * 256 + t;
        if (e < Etot) {
            int dst = (e < E) ? ei[E + e] : (int)(e - E);
            atomicAdd(&cnt[dst / width], 1);
        }
    }
    __syncthreads();
    for (int i = t; i < NB; i += 256) {
        int c = cnt[i];
        base[i] = c ? atomicAdd(&gcnt[i], c) : 0;
        cnt[i] = 0;
    }
    __syncthreads();
    for (int k = 0; k < BIN_CHUNK / 256; ++k) {
        long e = chunk0 + k * 256 + t;
        if (e < Etot) {
            int src, dst;
            if (e < E) { src = ei[e]; dst = ei[E + e]; }
            else       { src = (int)(e - E); dst = src; }
            int b = dst / width;
            size_t pos = (size_t)b * cap + base[b] + atomicAdd(&cnt[b], 1);
            binned[pos] = (unsigned)src | ((unsigned)(dst - b * width) << 17);
        }
    }
}

__global__ void bucket_scan(const int* __restrict__ gcnt, int Etot,
                            int* __restrict__ bbase, int* __restrict__ rp, int N) {
    __shared__ int s[NB];
    int t = threadIdx.x;
    int own = gcnt[t];
    s[t] = own;
    __syncthreads();
    for (int d = 1; d < NB; d <<= 1) {
        int add = (t >= d) ? s[t - d] : 0;
        __syncthreads();
        s[t] += add;
        __syncthreads();
    }
    bbase[t] = s[t] - own;
    if (t == NB - 1) bbase[NB] = s[t];
    if (t == 0) rp[N] = Etot;
}

__global__ __launch_bounds__(256) void bucket_sort(const unsigned* __restrict__ binned,
                                                   const int* __restrict__ gcnt,
                                                   const int* __restrict__ bbase,
                                                   int width, int cap, int N,
                                                   int* __restrict__ rp, int* __restrict__ srcs) {
    __shared__ int cnt[256];
    __shared__ int cur[256];
    int b = blockIdx.x, t = threadIdx.x;
    int r0 = bbase[b];
    int ne = gcnt[b];
    const unsigned* bin = binned + (size_t)b * cap;
    int nodeBase = b * width;
    cnt[t] = 0;
    cur[t] = 0;
    __syncthreads();
    for (int e = t; e < ne; e += 256) {
        atomicAdd(&cnt[bin[e] >> 17], 1);
    }
    __syncthreads();
    int own = cnt[t];
    for (int d = 1; d < 256; d <<= 1) {
        int add = (t >= d) ? cnt[t - d] : 0;
        __syncthreads();
        cnt[t] += add;
        __syncthreads();
    }
    int excl = cnt[t] - own;
    int node = nodeBase + t;
    if (t < width && node < N) rp[node] = r0 + excl;
    __syncthreads();
    cnt[t] = excl;
    __syncthreads();
    for (int e = t; e < ne; e += 256) {
        unsigned p = bin[e];
        int dL = p >> 17;
        int pos = r0 + cnt[dL] + atomicAdd(&cur[dL], 1);
        srcs[pos] = (int)(p & 0x1FFFFu);
    }
}

// ---------------- lin1: h = relu(x@W1^T+b1); write combined row [hn fp16 x16 | h fp16 x16] ----------------
__global__ __launch_bounds__(256) void lin1_relu(const float* __restrict__ x,
                                                 const float* __restrict__ W1,
                                                 const float* __restrict__ b1,
                                                 __half* __restrict__ hrow, int N) {
    __shared__ float4 w4[16 * 16 * 9];  // [j][s][m], slice stride 9 float4
    int t = threadIdx.x;
    for (int r = 0; r < 8; ++r) {
        int idx = r * 256 + t;
        int j = idx >> 7;
        int rem = idx & 127;
        int s = rem >> 3, m = rem & 7;
        w4[(j * 16 + s) * 9 + m] = ((const float4*)W1)[idx];
    }
    __syncthreads();

    int s = t & 15, g = t >> 4;
    int iA = blockIdx.x * 32 + g;
    int iB = iA + 16;
    int iAc = min(iA, N - 1), iBc = min(iB, N - 1);

    const float4* xA4 = (const float4*)(x + (size_t)iAc * F);
    const float4* xB4 = (const float4*)(x + (size_t)iBc * F);
    float4 xa[8], xb[8];
#pragma unroll
    for (int m = 0; m < 8; ++m) xa[m] = xA4[s * 8 + m];
#pragma unroll
    for (int m = 0; m < 8; ++m) xb[m] = xB4[s * 8 + m];

    float vA[16], vB[16];
#pragma unroll
    for (int j = 0; j < 16; ++j) { vA[j] = 0.f; vB[j] = 0.f; }
#pragma unroll
    for (int j = 0; j < 16; ++j) {
        const float4* wr = &w4[(j * 16 + s) * 9];
#pragma unroll
        for (int m = 0; m < 8; ++m) {
            float4 w = wr[m];
            vA[j] += w.x * xa[m].x + w.y * xa[m].y + w.z * xa[m].z + w.w * xa[m].w;
            vB[j] += w.x * xb[m].x + w.y * xb[m].y + w.z * xb[m].z + w.w * xb[m].w;
        }
    }

#pragma unroll
    for (int st = 0; st < 4; ++st) {
        int bit = (s >> st) & 1;
        int cntj = 16 >> (st + 1);
#pragma unroll
        for (int k = 0; k < 8; ++k) {
            if (k < cntj) {
                float keepA = bit ? vA[2 * k + 1] : vA[2 * k];
                float giveA = bit ? vA[2 * k] : vA[2 * k + 1];
                vA[k] = keepA + __shfl_xor(giveA, 1 << st);
                float keepB = bit ? vB[2 * k + 1] : vB[2 * k];
                float giveB = bit ? vB[2 * k] : vB[2 * k + 1];
                vB[k] = keepB + __shfl_xor(giveB, 1 << st);
            }
        }
    }

    float bs = b1[s];
    float oA = fmaxf(vA[0] + bs, 0.f);
    float oB = fmaxf(vB[0] + bs, 0.f);

    float sqA = oA * oA, sqB = oB * oB;
    sqA += __shfl_xor(sqA, 1); sqA += __shfl_xor(sqA, 2);
    sqA += __shfl_xor(sqA, 4); sqA += __shfl_xor(sqA, 8);
    sqB += __shfl_xor(sqB, 1); sqB += __shfl_xor(sqB, 2);
    sqB += __shfl_xor(sqB, 4); sqB += __shfl_xor(sqB, 8);
    float rnA = 1.0f / fmaxf(sqrtf(sqA), 1e-12f);
    float rnB = 1.0f / fmaxf(sqrtf(sqB), 1e-12f);

    if (iA < N) {
        hrow[(size_t)iA * 32 + s] = __float2half(oA * rnA);
        hrow[(size_t)iA * 32 + 16 + s] = __float2half(oA);
    }
    if (iB < N) {
        hrow[(size_t)iB * 32 + s] = __float2half(oB * rnB);
        hrow[(size_t)iB * 32 + 16 + s] = __float2half(oB);
    }
}

// ---------------- AGNN step v4: thread-per-dst, 64B combined rows, 4-deep pipeline ----------------
__global__ __launch_bounds__(64) void agnn_step(const uint4* __restrict__ hrow,
                                                const int* __restrict__ rp,
                                                const int* __restrict__ srcs,
                                                const float* __restrict__ bp,
                                                uint4* __restrict__ hrow_out, int N) {
    int i = blockIdx.x * 64 + threadIdx.x;
    if (i >= N) return;

    const float L2E = 1.4426950408889634f;
    float beta = bp ? bp[0] : 1.0f;
    float aL = beta * L2E;
    float mm = fabsf(beta) * L2E;

    // own normalized row (first 32B)
    uint4 hA = hrow[(size_t)i * 4 + 0];
    uint4 hB = hrow[(size_t)i * 4 + 1];
    h2 hi[8];
    hi[0] = as_h2(hA.x); hi[1] = as_h2(hA.y); hi[2] = as_h2(hA.z); hi[3] = as_h2(hA.w);
    hi[4] = as_h2(hB.x); hi[5] = as_h2(hB.y); hi[6] = as_h2(hB.z); hi[7] = as_h2(hB.w);

    int e0 = rp[i];
    int deg = rp[i + 1] - e0;
    int dm1 = deg - 1;

    int sbuf[4];
    uint4 rbuf[4][4];
#pragma unroll
    for (int u = 0; u < 4; ++u) {
        int s = srcs[e0 + min(u, dm1)];
        const uint4* r = hrow + (size_t)s * 4;
        rbuf[u][0] = r[0]; rbuf[u][1] = r[1]; rbuf[u][2] = r[2]; rbuf[u][3] = r[3];
        sbuf[u] = srcs[e0 + min(u + 4, dm1)];
    }

    float denom = 0.f;
    float acc[16];
#pragma unroll
    for (int j = 0; j < 16; ++j) acc[j] = 0.f;

    for (int k0 = 0; k0 < deg; k0 += 4) {
#pragma unroll
        for (int u = 0; u < 4; ++u) {
            int k = k0 + u;
            uint4 a = rbuf[u][0], b = rbuf[u][1], c = rbuf[u][2], d = rbuf[u][3];
            // prefetch: row for edge k+4 (addr from sbuf, loaded 4 iters ago), src for edge k+8
            int snext = sbuf[u];
            sbuf[u] = srcs[e0 + min(k + 8, dm1)];
            const uint4* r = hrow + (size_t)snext * 4;
            rbuf[u][0] = r[0]; rbuf[u][1] = r[1]; rbuf[u][2] = r[2]; rbuf[u][3] = r[3];

            float dot = 0.f;
            dot = dot2acc(hi[0], as_h2(a.x), dot);
            dot = dot2acc(hi[1], as_h2(a.y), dot);
            dot = dot2acc(hi[2], as_h2(a.z), dot);
            dot = dot2acc(hi[3], as_h2(a.w), dot);
            dot = dot2acc(hi[4], as_h2(b.x), dot);
            dot = dot2acc(hi[5], as_h2(b.y), dot);
            dot = dot2acc(hi[6], as_h2(b.z), dot);
            dot = dot2acc(hi[7], as_h2(b.w), dot);

            float w = exp2f(fmaf(aL, dot, -mm));
            w = (k < deg) ? w : 0.f;
            denom += w;

            h2 c0 = as_h2(c.x), c1 = as_h2(c.y), c2 = as_h2(c.z), c3 = as_h2(c.w);
            h2 d0 = as_h2(d.x), d1 = as_h2(d.y), d2 = as_h2(d.z), d3 = as_h2(d.w);
            acc[0]  = fmaf(w, (float)c0[0], acc[0]);
            acc[1]  = fmaf(w, (float)c0[1], acc[1]);
            acc[2]  = fmaf(w, (float)c1[0], acc[2]);
            acc[3]  = fmaf(w, (float)c1[1], acc[3]);
            acc[4]  = fmaf(w, (float)c2[0], acc[4]);
            acc[5]  = fmaf(w, (float)c2[1], acc[5]);
            acc[6]  = fmaf(w, (float)c3[0], acc[6]);
            acc[7]  = fmaf(w, (float)c3[1], acc[7]);
            acc[8]  = fmaf(w, (float)d0[0], acc[8]);
            acc[9]  = fmaf(w, (float)d0[1], acc[9]);
            acc[10] = fmaf(w, (float)d1[0], acc[10]);
            acc[11] = fmaf(w, (float)d1[1], acc[11]);
            acc[12] = fmaf(w, (float)d2[0], acc[12]);
            acc[13] = fmaf(w, (float)d2[1], acc[13]);
            acc[14] = fmaf(w, (float)d3[0], acc[14]);
            acc[15] = fmaf(w, (float)d3[1], acc[15]);
        }
    }

    float rd = 1.0f / denom;
    float o[16];
    float sq = 0.f;
#pragma unroll
    for (int j = 0; j < 16; ++j) {
        o[j] = acc[j] * rd;
        sq = fmaf(o[j], o[j], sq);
    }
    float rno = 1.0f / fmaxf(sqrtf(sq), 1e-12f);

    uint4 w0, w1, w2, w3;
    {
        h2 t0, t1;
        t0[0] = (_Float16)(o[0] * rno);  t0[1] = (_Float16)(o[1] * rno);
        t1[0] = (_Float16)(o[2] * rno);  t1[1] = (_Float16)(o[3] * rno);
        w0.x = as_u32(t0); w0.y = as_u32(t1);
        t0[0] = (_Float16)(o[4] * rno);  t0[1] = (_Float16)(o[5] * rno);
        t1[0] = (_Float16)(o[6] * rno);  t1[1] = (_Float16)(o[7] * rno);
        w0.z = as_u32(t0); w0.w = as_u32(t1);
        t0[0] = (_Float16)(o[8] * rno);  t0[1] = (_Float16)(o[9] * rno);
        t1[0] = (_Float16)(o[10] * rno); t1[1] = (_Float16)(o[11] * rno);
        w1.x = as_u32(t0); w1.y = as_u32(t1);
        t0[0] = (_Float16)(o[12] * rno); t0[1] = (_Float16)(o[13] * rno);
        t1[0] = (_Float16)(o[14] * rno); t1[1] = (_Float16)(o[15] * rno);
        w1.z = as_u32(t0); w1.w = as_u32(t1);
        t0[0] = (_Float16)o[0];  t0[1] = (_Float16)o[1];
        t1[0] = (_Float16)o[2];  t1[1] = (_Float16)o[3];
        w2.x = as_u32(t0); w2.y = as_u32(t1);
        t0[0] = (_Float16)o[4];  t0[1] = (_Float16)o[5];
        t1[0] = (_Float16)o[6];  t1[1] = (_Float16)o[7];
        w2.z = as_u32(t0); w2.w = as_u32(t1);
        t0[0] = (_Float16)o[8];  t0[1] = (_Float16)o[9];
        t1[0] = (_Float16)o[10]; t1[1] = (_Float16)o[11];
        w3.x = as_u32(t0); w3.y = as_u32(t1);
        t0[0] = (_Float16)o[12]; t0[1] = (_Float16)o[13];
        t1[0] = (_Float16)o[14]; t1[1] = (_Float16)o[15];
        w3.z = as_u32(t0); w3.w = as_u32(t1);
    }
    uint4* op = hrow_out + (size_t)i * 4;
    op[0] = w0; op[1] = w1; op[2] = w2; op[3] = w3;
}

// ---------------- head: logits + log_softmax (reads h part of combined row) ----------------
__global__ __launch_bounds__(256) void head_kernel(const uint4* __restrict__ hrow,
                                                   const float* __restrict__ W2,
                                                   const float* __restrict__ b2,
                                                   float* __restrict__ out, int N) {
    __shared__ float w2[C * H];
    __shared__ float bb[C];
    int t = threadIdx.x;
    if (t < C * H) w2[t] = W2[t];
    if (t < C) bb[t] = b2[t];
    __syncthreads();
    int i = blockIdx.x * blockDim.x + t;
    if (i >= N) return;
    uint4 cA = hrow[(size_t)i * 4 + 2];
    uint4 cB = hrow[(size_t)i * 4 + 3];
    float hv[H];
    {
        h2 v;
        v = as_h2(cA.x); hv[0] = (float)v[0];  hv[1] = (float)v[1];
        v = as_h2(cA.y); hv[2] = (float)v[0];  hv[3] = (float)v[1];
        v = as_h2(cA.z); hv[4] = (float)v[0];  hv[5] = (float)v[1];
        v = as_h2(cA.w); hv[6] = (float)v[0];  hv[7] = (float)v[1];
        v = as_h2(cB.x); hv[8] = (float)v[0];  hv[9] = (float)v[1];
        v = as_h2(cB.y); hv[10] = (float)v[0]; hv[11] = (float)v[1];
        v = as_h2(cB.z); hv[12] = (float)v[0]; hv[13] = (float)v[1];
        v = as_h2(cB.w); hv[14] = (float)v[0]; hv[15] = (float)v[1];
    }
    float lg[C];
    float m = -1e30f;
#pragma unroll
    for (int c = 0; c < C; ++c) {
        float s = bb[c];
#pragma unroll
        for (int k = 0; k < H; ++k) s += hv[k] * w2[c * H + k];
        lg[c] = s;
        m = fmaxf(m, s);
    }
    float sum = 0.f;
#pragma unroll
    for (int c = 0; c < C; ++c) sum += expf(lg[c] - m);
    float lse = m + logf(sum);
    float* op = out + (size_t)i * C;
#pragma unroll
    for (int c = 0; c < C; ++c) op[c] = lg[c] - lse;
}

// ---------------- launch ----------------
extern "C" void kernel_launch(void* const* d_in, const int* in_sizes, int n_in,
                              void* d_out, int out_size, void* d_ws, size_t ws_size,
                              hipStream_t stream) {
    const float* x     = (const float*)d_in[0];
    const int*   ei    = (const int*)d_in[1];
    const float* W1    = (const float*)d_in[2];
    const float* b1    = (const float*)d_in[3];
    const float* beta2 = (const float*)d_in[4];
    const float* beta3 = (const float*)d_in[5];
    const float* beta4 = (const float*)d_in[6];
    const float* W2    = (const float*)d_in[7];
    const float* b2    = (const float*)d_in[8];
    float* out = (float*)d_out;

    int N = in_sizes[0] / F;     // 100000
    int E = in_sizes[1] / 2;     // 3200000
    int Etot = E + N;
    int width = (N + NB - 1) / NB;   // 196
    int cap = (Etot / NB) * 5 / 4;   // 1.25x mean bucket size (>20 sigma margin)

    char* p = (char*)d_ws;
    uint4* hr_a = (uint4*)p; p += (size_t)N * 64;
    uint4* hr_b = (uint4*)p; p += (size_t)N * 64;
    int* rp     = (int*)p;   p += (size_t)(N + 1) * 4;
    int* srcs   = (int*)p;   p += (size_t)Etot * 4;
    int* gcnt   = (int*)p;   p += (size_t)NB * 4;
    int* bbase  = (int*)p;   p += (size_t)(NB + 1) * 4;
    p = (char*)(((size_t)p + 255) & ~(size_t)255);
    unsigned* binned = (unsigned*)p; p += (size_t)NB * cap * 4;

    // CSR build
    zero_i32<<<(NB + 255) / 256, 256, 0, stream>>>(gcnt, NB);
    bin_edges<<<(Etot + BIN_CHUNK - 1) / BIN_CHUNK, 256, 0, stream>>>(ei, E, Etot, width, cap, gcnt, binned);
    bucket_scan<<<1, NB, 0, stream>>>(gcnt, Etot, bbase, rp, N);
    bucket_sort<<<NB, 256, 0, stream>>>(binned, gcnt, bbase, width, cap, N, rp, srcs);

    // lin1 -> combined rows
    lin1_relu<<<(N + 31) / 32, 256, 0, stream>>>(x, W1, b1, (__half*)hr_a, N);

    // 4 AGNN steps (thread-per-dst)
    int gs = (N + 63) / 64;
    agnn_step<<<gs, 64, 0, stream>>>(hr_a, rp, srcs, nullptr, hr_b, N);
    agnn_step<<<gs, 64, 0, stream>>>(hr_b, rp, srcs, beta2, hr_a, N);
    agnn_step<<<gs, 64, 0, stream>>>(hr_a, rp, srcs, beta3, hr_b, N);
    agnn_step<<<gs, 64, 0, stream>>>(hr_b, rp, srcs, beta4, hr_a, N);

    // head
    head_kernel<<<(N + 255) / 256, 256, 0, stream>>>(hr_a, W2, b2, out, N);
}

// Round 6
// 604.292 us; speedup vs baseline: 2.1144x; 1.0870x over previous
//
#include <hip/hip_runtime.h>
#include <hip/hip_fp16.h>
#include <math.h>

#define F 512
#define H 16
#define C 7
#define NB 512          // coarse buckets for CSR build
#define BIN_CHUNK 4096  // edges per block in bin_edges

typedef _Float16 h2 __attribute__((ext_vector_type(2)));

__device__ __forceinline__ h2 as_h2(unsigned u) { return __builtin_bit_cast(h2, u); }
__device__ __forceinline__ unsigned as_u32(h2 v) { return __builtin_bit_cast(unsigned, v); }

__device__ __forceinline__ float dot2acc(h2 a, h2 b, float c) {
#if __has_builtin(__builtin_amdgcn_fdot2)
    return __builtin_amdgcn_fdot2(a, b, c, false);
#else
    return c + (float)a[0] * (float)b[0] + (float)a[1] * (float)b[1];
#endif
}

// ---------------- utility ----------------
__global__ void zero_i32(int* p, int n) {
    int i = blockIdx.x * blockDim.x + threadIdx.x;
    if (i < n) p[i] = 0;
}

// ---------------- CSR build: 3 kernels, fixed-capacity buckets ----------------
__global__ __launch_bounds__(256) void bin_edges(const int* __restrict__ ei, int E, int Etot,
                                                 int width, int cap, int* __restrict__ gcnt,
                                                 unsigned* __restrict__ binned) {
    __shared__ int cnt[NB];
    __shared__ int base[NB];
    int t = threadIdx.x;
    for (int i = t; i < NB; i += 256) cnt[i] = 0;
    __syncthreads();
    long chunk0 = (long)blockIdx.x * BIN_CHUNK;
    for (int k = 0; k < BIN_CHUNK / 256; ++k) {
        long e = chunk0 + k * 256 + t;
        if (e < Etot) {
            int dst = (e < E) ? ei[E + e] : (int)(e - E);
            atomicAdd(&cnt[dst / width], 1);
        }
    }
    __syncthreads();
    for (int i = t; i < NB; i += 256) {
        int c = cnt[i];
        base[i] = c ? atomicAdd(&gcnt[i], c) : 0;
        cnt[i] = 0;
    }
    __syncthreads();
    for (int k = 0; k < BIN_CHUNK / 256; ++k) {
        long e = chunk0 + k * 256 + t;
        if (e < Etot) {
            int src, dst;
            if (e < E) { src = ei[e]; dst = ei[E + e]; }
            else       { src = (int)(e - E); dst = src; }
            int b = dst / width;
            size_t pos = (size_t)b * cap + base[b] + atomicAdd(&cnt[b], 1);
            binned[pos] = (unsigned)src | ((unsigned)(dst - b * width) << 17);
        }
    }
}

__global__ void bucket_scan(const int* __restrict__ gcnt, int Etot,
                            int* __restrict__ bbase, int* __restrict__ rp, int N) {
    __shared__ int s[NB];
    int t = threadIdx.x;
    int own = gcnt[t];
    s[t] = own;
    __syncthreads();
    for (int d = 1; d < NB; d <<= 1) {
        int add = (t >= d) ? s[t - d] : 0;
        __syncthreads();
        s[t] += add;
        __syncthreads();
    }
    bbase[t] = s[t] - own;
    if (t == NB - 1) bbase[NB] = s[t];
    if (t == 0) rp[N] = Etot;
}

__global__ __launch_bounds__(256) void bucket_sort(const unsigned* __restrict__ binned,
                                                   const int* __restrict__ gcnt,
                                                   const int* __restrict__ bbase,
                                                   int width, int cap, int N,
                                                   int* __restrict__ rp, int* __restrict__ srcs) {
    __shared__ int cnt[256];
    __shared__ int cur[256];
    int b = blockIdx.x, t = threadIdx.x;
    int r0 = bbase[b];
    int ne = gcnt[b];
    const unsigned* bin = binned + (size_t)b * cap;
    int nodeBase = b * width;
    cnt[t] = 0;
    cur[t] = 0;
    __syncthreads();
    for (int e = t; e < ne; e += 256) {
        atomicAdd(&cnt[bin[e] >> 17], 1);
    }
    __syncthreads();
    int own = cnt[t];
    for (int d = 1; d < 256; d <<= 1) {
        int add = (t >= d) ? cnt[t - d] : 0;
        __syncthreads();
        cnt[t] += add;
        __syncthreads();
    }
    int excl = cnt[t] - own;
    int node = nodeBase + t;
    if (t < width && node < N) rp[node] = r0 + excl;
    __syncthreads();
    cnt[t] = excl;
    __syncthreads();
    for (int e = t; e < ne; e += 256) {
        unsigned p = bin[e];
        int dL = p >> 17;
        int pos = r0 + cnt[dL] + atomicAdd(&cur[dL], 1);
        srcs[pos] = (int)(p & 0x1FFFFu);
    }
}

// ---------------- lin1: h = relu(x@W1^T+b1); write combined row [hn fp16 x16 | h fp16 x16] ----------------
__global__ __launch_bounds__(256) void lin1_relu(const float* __restrict__ x,
                                                 const float* __restrict__ W1,
                                                 const float* __restrict__ b1,
                                                 __half* __restrict__ hrow, int N) {
    __shared__ float4 w4[16 * 16 * 9];  // [j][s][m], slice stride 9 float4
    int t = threadIdx.x;
    for (int r = 0; r < 8; ++r) {
        int idx = r * 256 + t;
        int j = idx >> 7;
        int rem = idx & 127;
        int s = rem >> 3, m = rem & 7;
        w4[(j * 16 + s) * 9 + m] = ((const float4*)W1)[idx];
    }
    __syncthreads();

    int s = t & 15, g = t >> 4;
    int iA = blockIdx.x * 32 + g;
    int iB = iA + 16;
    int iAc = min(iA, N - 1), iBc = min(iB, N - 1);

    const float4* xA4 = (const float4*)(x + (size_t)iAc * F);
    const float4* xB4 = (const float4*)(x + (size_t)iBc * F);
    float4 xa[8], xb[8];
#pragma unroll
    for (int m = 0; m < 8; ++m) xa[m] = xA4[s * 8 + m];
#pragma unroll
    for (int m = 0; m < 8; ++m) xb[m] = xB4[s * 8 + m];

    float vA[16], vB[16];
#pragma unroll
    for (int j = 0; j < 16; ++j) { vA[j] = 0.f; vB[j] = 0.f; }
#pragma unroll
    for (int j = 0; j < 16; ++j) {
        const float4* wr = &w4[(j * 16 + s) * 9];
#pragma unroll
        for (int m = 0; m < 8; ++m) {
            float4 w = wr[m];
            vA[j] += w.x * xa[m].x + w.y * xa[m].y + w.z * xa[m].z + w.w * xa[m].w;
            vB[j] += w.x * xb[m].x + w.y * xb[m].y + w.z * xb[m].z + w.w * xb[m].w;
        }
    }

#pragma unroll
    for (int st = 0; st < 4; ++st) {
        int bit = (s >> st) & 1;
        int cntj = 16 >> (st + 1);
#pragma unroll
        for (int k = 0; k < 8; ++k) {
            if (k < cntj) {
                float keepA = bit ? vA[2 * k + 1] : vA[2 * k];
                float giveA = bit ? vA[2 * k] : vA[2 * k + 1];
                vA[k] = keepA + __shfl_xor(giveA, 1 << st);
                float keepB = bit ? vB[2 * k + 1] : vB[2 * k];
                float giveB = bit ? vB[2 * k] : vB[2 * k + 1];
                vB[k] = keepB + __shfl_xor(giveB, 1 << st);
            }
        }
    }

    float bs = b1[s];
    float oA = fmaxf(vA[0] + bs, 0.f);
    float oB = fmaxf(vB[0] + bs, 0.f);

    float sqA = oA * oA, sqB = oB * oB;
    sqA += __shfl_xor(sqA, 1); sqA += __shfl_xor(sqA, 2);
    sqA += __shfl_xor(sqA, 4); sqA += __shfl_xor(sqA, 8);
    sqB += __shfl_xor(sqB, 1); sqB += __shfl_xor(sqB, 2);
    sqB += __shfl_xor(sqB, 4); sqB += __shfl_xor(sqB, 8);
    float rnA = 1.0f / fmaxf(sqrtf(sqA), 1e-12f);
    float rnB = 1.0f / fmaxf(sqrtf(sqB), 1e-12f);

    if (iA < N) {
        hrow[(size_t)iA * 32 + s] = __float2half(oA * rnA);
        hrow[(size_t)iA * 32 + 16 + s] = __float2half(oA);
    }
    if (iB < N) {
        hrow[(size_t)iB * 32 + s] = __float2half(oB * rnB);
        hrow[(size_t)iB * 32 + 16 + s] = __float2half(oB);
    }
}

// ---------------- AGNN step v5: 4 sub-lanes per dst (stride-4 edge split), 64B rows ----------------
// i = (blockIdx*256 + t)/4, sub = t&3. Sub-lane handles edges e0+sub, e0+sub+4, ...
// Uniform trip count U = ceil(deg/4) keeps the 4 sub-lanes converged; invalid -> w=0.
__global__ __launch_bounds__(256) void agnn_step(const uint4* __restrict__ hrow,
                                                 const int* __restrict__ rp,
                                                 const int* __restrict__ srcs,
                                                 const float* __restrict__ bp,
                                                 uint4* __restrict__ hrow_out, int N) {
    int t = threadIdx.x;
    int sub = t & 3, g = t >> 2;
    int i = blockIdx.x * 64 + g;
    if (i >= N) return;

    const float L2E = 1.4426950408889634f;
    float beta = bp ? bp[0] : 1.0f;
    float aL = beta * L2E;
    float mm = fabsf(beta) * L2E;

    // own normalized row (first 32B)
    uint4 hA = hrow[(size_t)i * 4 + 0];
    uint4 hB = hrow[(size_t)i * 4 + 1];
    h2 hi[8];
    hi[0] = as_h2(hA.x); hi[1] = as_h2(hA.y); hi[2] = as_h2(hA.z); hi[3] = as_h2(hA.w);
    hi[4] = as_h2(hB.x); hi[5] = as_h2(hB.y); hi[6] = as_h2(hB.z); hi[7] = as_h2(hB.w);

    int e0 = rp[i];
    int deg = rp[i + 1] - e0;
    int dm1 = deg - 1;
    int U = (deg + 3) >> 2;   // uniform across the 4 sub-lanes of this dst

    // ring: slot u holds row of edge m=mb+u (lane edge k = sub+4m); sbuf[u] = src of edge m+4
    int sbuf[4];
    uint4 rbuf[4][4];
#pragma unroll
    for (int u = 0; u < 4; ++u) {
        int s = srcs[e0 + min(sub + 4 * u, dm1)];
        const uint4* r = hrow + (size_t)s * 4;
        rbuf[u][0] = r[0]; rbuf[u][1] = r[1]; rbuf[u][2] = r[2]; rbuf[u][3] = r[3];
        sbuf[u] = srcs[e0 + min(sub + 4 * (u + 4), dm1)];
    }

    float denom = 0.f;
    float acc[16];
#pragma unroll
    for (int j = 0; j < 16; ++j) acc[j] = 0.f;

    for (int mb = 0; mb < U; mb += 4) {
#pragma unroll
        for (int u = 0; u < 4; ++u) {
            int m = mb + u;
            int k = sub + 4 * m;
            uint4 a = rbuf[u][0], b = rbuf[u][1], c = rbuf[u][2], d = rbuf[u][3];
            // refill slot u with row of edge m+4; prefetch src of edge m+8
            int snext = sbuf[u];
            sbuf[u] = srcs[e0 + min(sub + 4 * (m + 8), dm1)];
            const uint4* r = hrow + (size_t)snext * 4;
            rbuf[u][0] = r[0]; rbuf[u][1] = r[1]; rbuf[u][2] = r[2]; rbuf[u][3] = r[3];

            float dot = 0.f;
            dot = dot2acc(hi[0], as_h2(a.x), dot);
            dot = dot2acc(hi[1], as_h2(a.y), dot);
            dot = dot2acc(hi[2], as_h2(a.z), dot);
            dot = dot2acc(hi[3], as_h2(a.w), dot);
            dot = dot2acc(hi[4], as_h2(b.x), dot);
            dot = dot2acc(hi[5], as_h2(b.y), dot);
            dot = dot2acc(hi[6], as_h2(b.z), dot);
            dot = dot2acc(hi[7], as_h2(b.w), dot);

            float w = exp2f(fmaf(aL, dot, -mm));
            w = (k < deg) ? w : 0.f;
            denom += w;

            h2 c0 = as_h2(c.x), c1 = as_h2(c.y), c2 = as_h2(c.z), c3 = as_h2(c.w);
            h2 d0 = as_h2(d.x), d1 = as_h2(d.y), d2 = as_h2(d.z), d3 = as_h2(d.w);
            acc[0]  = fmaf(w, (float)c0[0], acc[0]);
            acc[1]  = fmaf(w, (float)c0[1], acc[1]);
            acc[2]  = fmaf(w, (float)c1[0], acc[2]);
            acc[3]  = fmaf(w, (float)c1[1], acc[3]);
            acc[4]  = fmaf(w, (float)c2[0], acc[4]);
            acc[5]  = fmaf(w, (float)c2[1], acc[5]);
            acc[6]  = fmaf(w, (float)c3[0], acc[6]);
            acc[7]  = fmaf(w, (float)c3[1], acc[7]);
            acc[8]  = fmaf(w, (float)d0[0], acc[8]);
            acc[9]  = fmaf(w, (float)d0[1], acc[9]);
            acc[10] = fmaf(w, (float)d1[0], acc[10]);
            acc[11] = fmaf(w, (float)d1[1], acc[11]);
            acc[12] = fmaf(w, (float)d2[0], acc[12]);
            acc[13] = fmaf(w, (float)d2[1], acc[13]);
            acc[14] = fmaf(w, (float)d3[0], acc[14]);
            acc[15] = fmaf(w, (float)d3[1], acc[15]);
        }
    }

    // combine the 4 sub-lanes (lanes 4g..4g+3)
    denom += __shfl_xor(denom, 1);
    denom += __shfl_xor(denom, 2);
#pragma unroll
    for (int j = 0; j < 16; ++j) {
        acc[j] += __shfl_xor(acc[j], 1);
        acc[j] += __shfl_xor(acc[j], 2);
    }

    float rd = 1.0f / denom;
    float o[16];
    float sq = 0.f;
#pragma unroll
    for (int j = 0; j < 16; ++j) {
        o[j] = acc[j] * rd;
        sq = fmaf(o[j], o[j], sq);
    }
    float rno = 1.0f / fmaxf(sqrtf(sq), 1e-12f);

    // each sub-lane writes one 16B quarter: sub0=hn[0..7], sub1=hn[8..15], sub2=h[0..7], sub3=h[8..15]
    float scale = (sub < 2) ? rno : 1.0f;
    int half = (sub & 1) * 8;
    uint4 wq;
    {
        h2 t0, t1;
        t0[0] = (_Float16)(o[half + 0] * scale); t0[1] = (_Float16)(o[half + 1] * scale);
        t1[0] = (_Float16)(o[half + 2] * scale); t1[1] = (_Float16)(o[half + 3] * scale);
        wq.x = as_u32(t0); wq.y = as_u32(t1);
        t0[0] = (_Float16)(o[half + 4] * scale); t0[1] = (_Float16)(o[half + 5] * scale);
        t1[0] = (_Float16)(o[half + 6] * scale); t1[1] = (_Float16)(o[half + 7] * scale);
        wq.z = as_u32(t0); wq.w = as_u32(t1);
    }
    hrow_out[(size_t)i * 4 + sub] = wq;
}

// ---------------- head: logits + log_softmax (reads h part of combined row) ----------------
__global__ __launch_bounds__(256) void head_kernel(const uint4* __restrict__ hrow,
                                                   const float* __restrict__ W2,
                                                   const float* __restrict__ b2,
                                                   float* __restrict__ out, int N) {
    __shared__ float w2[C * H];
    __shared__ float bb[C];
    int t = threadIdx.x;
    if (t < C * H) w2[t] = W2[t];
    if (t < C) bb[t] = b2[t];
    __syncthreads();
    int i = blockIdx.x * blockDim.x + t;
    if (i >= N) return;
    uint4 cA = hrow[(size_t)i * 4 + 2];
    uint4 cB = hrow[(size_t)i * 4 + 3];
    float hv[H];
    {
        h2 v;
        v = as_h2(cA.x); hv[0] = (float)v[0];  hv[1] = (float)v[1];
        v = as_h2(cA.y); hv[2] = (float)v[0];  hv[3] = (float)v[1];
        v = as_h2(cA.z); hv[4] = (float)v[0];  hv[5] = (float)v[1];
        v = as_h2(cA.w); hv[6] = (float)v[0];  hv[7] = (float)v[1];
        v = as_h2(cB.x); hv[8] = (float)v[0];  hv[9] = (float)v[1];
        v = as_h2(cB.y); hv[10] = (float)v[0]; hv[11] = (float)v[1];
        v = as_h2(cB.z); hv[12] = (float)v[0]; hv[13] = (float)v[1];
        v = as_h2(cB.w); hv[14] = (float)v[0]; hv[15] = (float)v[1];
    }
    float lg[C];
    float m = -1e30f;
#pragma unroll
    for (int c = 0; c < C; ++c) {
        float s = bb[c];
#pragma unroll
        for (int k = 0; k < H; ++k) s += hv[k] * w2[c * H + k];
        lg[c] = s;
        m = fmaxf(m, s);
    }
    float sum = 0.f;
#pragma unroll
    for (int c = 0; c < C; ++c) sum += expf(lg[c] - m);
    float lse = m + logf(sum);
    float* op = out + (size_t)i * C;
#pragma unroll
    for (int c = 0; c < C; ++c) op[c] = lg[c] - lse;
}

// ---------------- launch ----------------
extern "C" void kernel_launch(void* const* d_in, const int* in_sizes, int n_in,
                              void* d_out, int out_size, void* d_ws, size_t ws_size,
                              hipStream_t stream) {
    const float* x     = (const float*)d_in[0];
    const int*   ei    = (const int*)d_in[1];
    const float* W1    = (const float*)d_in[2];
    const float* b1    = (const float*)d_in[3];
    const float* beta2 = (const float*)d_in[4];
    const float* beta3 = (const float*)d_in[5];
    const float* beta4 = (const float*)d_in[6];
    const float* W2    = (const float*)d_in[7];
    const float* b2    = (const float*)d_in[8];
    float* out = (float*)d_out;

    int N = in_sizes[0] / F;     // 100000
    int E = in_sizes[1] / 2;     // 3200000
    int Etot = E + N;
    int width = (N + NB - 1) / NB;   // 196
    int cap = (Etot / NB) * 5 / 4;   // 1.25x mean bucket size (>20 sigma margin)

    char* p = (char*)d_ws;
    uint4* hr_a = (uint4*)p; p += (size_t)N * 64;
    uint4* hr_b = (uint4*)p; p += (size_t)N * 64;
    int* rp     = (int*)p;   p += (size_t)(N + 1) * 4;
    int* srcs   = (int*)p;   p += (size_t)Etot * 4;
    int* gcnt   = (int*)p;   p += (size_t)NB * 4;
    int* bbase  = (int*)p;   p += (size_t)(NB + 1) * 4;
    p = (char*)(((size_t)p + 255) & ~(size_t)255);
    unsigned* binned = (unsigned*)p; p += (size_t)NB * cap * 4;

    // CSR build
    zero_i32<<<(NB + 255) / 256, 256, 0, stream>>>(gcnt, NB);
    bin_edges<<<(Etot + BIN_CHUNK - 1) / BIN_CHUNK, 256, 0, stream>>>(ei, E, Etot, width, cap, gcnt, binned);
    bucket_scan<<<1, NB, 0, stream>>>(gcnt, Etot, bbase, rp, N);
    bucket_sort<<<NB, 256, 0, stream>>>(binned, gcnt, bbase, width, cap, N, rp, srcs);

    // lin1 -> combined rows
    lin1_relu<<<(N + 31) / 32, 256, 0, stream>>>(x, W1, b1, (__half*)hr_a, N);

    // 4 AGNN steps (4 sub-lanes per dst)
    int gs = (N + 63) / 64;
    agnn_step<<<gs, 256, 0, stream>>>(hr_a, rp, srcs, nullptr, hr_b, N);
    agnn_step<<<gs, 256, 0, stream>>>(hr_b, rp, srcs, beta2, hr_a, N);
    agnn_step<<<gs, 256, 0, stream>>>(hr_a, rp, srcs, beta3, hr_b, N);
    agnn_step<<<gs, 256, 0, stream>>>(hr_b, rp, srcs, beta4, hr_a, N);

    // head
    head_kernel<<<(N + 255) / 256, 256, 0, stream>>>(hr_a, W2, b2, out, N);
}